// Round 1
// baseline (2570.344 us; speedup 1.0000x reference)
//
#include <hip/hip_runtime.h>
#include <stdint.h>

#define L_TOK 16384
#define DM 256
#define DI 512
#define DS 64
#define NH 8
#define HD 64
#define CD 640
#define DP 1160
#define CHUNK 64
#define NC 256
#define EPSF 1e-5f

__device__ __forceinline__ float warp_sum(float v) {
  v += __shfl_xor(v, 1, 64);
  v += __shfl_xor(v, 2, 64);
  v += __shfl_xor(v, 4, 64);
  v += __shfl_xor(v, 8, 64);
  v += __shfl_xor(v, 16, 64);
  v += __shfl_xor(v, 32, 64);
  return v;
}

__device__ __forceinline__ float dot4f(const float4 a, const float4 b) {
  return a.x*b.x + a.y*b.y + a.z*b.z + a.w*b.w;
}

__device__ __forceinline__ float siluf(float x) { return x / (1.0f + expf(-x)); }

// ---------------- serialization ----------------

__global__ __launch_bounds__(256) void minmax_kernel(const float* __restrict__ pos, float* __restrict__ pmm) {
  __shared__ float sm[6][256];
  int tid = threadIdx.x;
  float mn0=1e30f, mn1=1e30f, mn2=1e30f, mx0=-1e30f, mx1=-1e30f, mx2=-1e30f;
  for (int t = tid; t < L_TOK; t += 256) {
    float a = pos[t*3+0], b = pos[t*3+1], c = pos[t*3+2];
    mn0=fminf(mn0,a); mx0=fmaxf(mx0,a);
    mn1=fminf(mn1,b); mx1=fmaxf(mx1,b);
    mn2=fminf(mn2,c); mx2=fmaxf(mx2,c);
  }
  sm[0][tid]=mn0; sm[1][tid]=mn1; sm[2][tid]=mn2;
  sm[3][tid]=mx0; sm[4][tid]=mx1; sm[5][tid]=mx2;
  __syncthreads();
  for (int s = 128; s > 0; s >>= 1) {
    if (tid < s) {
      #pragma unroll
      for (int d = 0; d < 3; ++d) {
        sm[d][tid]   = fminf(sm[d][tid],   sm[d][tid+s]);
        sm[3+d][tid] = fmaxf(sm[3+d][tid], sm[3+d][tid+s]);
      }
    }
    __syncthreads();
  }
  if (tid < 6) pmm[tid] = sm[tid][0];
}

__device__ unsigned int hilbert3(unsigned int a, unsigned int b, unsigned int c) {
  unsigned int x0 = a, x1 = b, x2 = c;
  for (unsigned int Q = 512u; Q > 1u; Q >>= 1) {
    unsigned int P = Q - 1u;
    // i = 0
    {
      unsigned int t = (x0 ^ x0) & P; (void)t;
      if (x0 & Q) x0 ^= P;
    }
    // i = 1
    {
      unsigned int t = (x0 ^ x1) & P;
      if (x1 & Q) { x0 ^= P; }
      else { x0 ^= t; x1 ^= t; }
    }
    // i = 2
    {
      unsigned int t = (x0 ^ x2) & P;
      if (x2 & Q) { x0 ^= P; }
      else { x0 ^= t; x2 ^= t; }
    }
  }
  x1 ^= x0; x2 ^= x1;
  unsigned int tt = 0;
  for (unsigned int Q = 512u; Q > 1u; Q >>= 1)
    if (x2 & Q) tt ^= (Q - 1u);
  x0 ^= tt; x1 ^= tt; x2 ^= tt;
  unsigned int code = 0;
  #pragma unroll
  for (int bb = 9; bb >= 0; --bb) {
    code = (code << 1) | ((x0 >> bb) & 1u);
    code = (code << 1) | ((x1 >> bb) & 1u);
    code = (code << 1) | ((x2 >> bb) & 1u);
  }
  return code;
}

__global__ __launch_bounds__(256) void hilbert_kernel(const float* __restrict__ pos, const float* __restrict__ pmm,
                                                      unsigned long long* __restrict__ keys) {
  int t = blockIdx.x*256 + threadIdx.x;
  if (t >= L_TOK) return;
  unsigned int g[3];
  #pragma unroll
  for (int d = 0; d < 3; ++d) {
    float v = (pos[t*3+d] - pmm[d]) / (pmm[3+d] - pmm[d] + 1e-6f) * 1023.0f;
    v = fminf(fmaxf(v, 0.0f), 1023.0f);
    g[d] = (unsigned int)(int)v;
  }
  unsigned int ca = hilbert3(g[0], g[1], g[2]);
  unsigned int cb = hilbert3(g[1], g[0], g[2]);
  keys[t]         = ((unsigned long long)ca << 14) | (unsigned long long)t;
  keys[L_TOK + t] = ((unsigned long long)cb << 14) | (unsigned long long)t;
}

__global__ __launch_bounds__(1024) void sort_kernel(unsigned long long* __restrict__ keys, unsigned int* __restrict__ ord) {
  unsigned long long* k = keys + (size_t)blockIdx.x * L_TOK;
  unsigned int* o = ord + (size_t)blockIdx.x * L_TOK;
  for (int kk = 2; kk <= L_TOK; kk <<= 1) {
    for (int j = kk >> 1; j > 0; j >>= 1) {
      for (int i = threadIdx.x; i < L_TOK; i += 1024) {
        int l = i ^ j;
        if (l > i) {
          unsigned long long a = k[i], b = k[l];
          bool up = ((i & kk) == 0);
          if ((a > b) == up) { k[i] = b; k[l] = a; }
        }
      }
      __syncthreads();
    }
  }
  for (int i = threadIdx.x; i < L_TOK; i += 1024)
    o[i] = (unsigned int)(k[i] & 0x3FFFu);
}

// ---------------- layernorm / gating ----------------

__global__ __launch_bounds__(256) void ln_kernel(const float* __restrict__ in, float* __restrict__ out,
                                                 const float* __restrict__ w, const float* __restrict__ b) {
  int row = blockIdx.x*4 + (threadIdx.x >> 6);
  int lane = threadIdx.x & 63;
  const float4 v = *(const float4*)(in + (size_t)row*DM + lane*4);
  float s = v.x + v.y + v.z + v.w;
  float mean = warp_sum(s) * (1.0f/DM);
  float4 xc = make_float4(v.x-mean, v.y-mean, v.z-mean, v.w-mean);
  float ss = xc.x*xc.x + xc.y*xc.y + xc.z*xc.z + xc.w*xc.w;
  ss = warp_sum(ss) * (1.0f/DM);
  float inv = rsqrtf(ss + EPSF);
  const float4 w4 = *(const float4*)(w + lane*4);
  const float4 b4 = *(const float4*)(b + lane*4);
  float4 o;
  o.x = xc.x*inv*w4.x + b4.x;
  o.y = xc.y*inv*w4.y + b4.y;
  o.z = xc.z*inv*w4.z + b4.z;
  o.w = xc.w*inv*w4.w + b4.w;
  *(float4*)(out + (size_t)row*DM + lane*4) = o;
}

__global__ __launch_bounds__(256) void gating_kernel(float* __restrict__ y, const float* __restrict__ gate,
                                                     const float* __restrict__ nw) {
  int row = blockIdx.x*4 + (threadIdx.x >> 6);
  int lane = threadIdx.x & 63;
  float* yr = y + (size_t)row*DI;
  const float* gr = gate + (size_t)row*DI;
  float4 y0 = *(float4*)(yr + lane*4);
  float4 y1 = *(float4*)(yr + 256 + lane*4);
  const float4 g0 = *(const float4*)(gr + lane*4);
  const float4 g1 = *(const float4*)(gr + 256 + lane*4);
  y0.x *= siluf(g0.x); y0.y *= siluf(g0.y); y0.z *= siluf(g0.z); y0.w *= siluf(g0.w);
  y1.x *= siluf(g1.x); y1.y *= siluf(g1.y); y1.z *= siluf(g1.z); y1.w *= siluf(g1.w);
  float ss = y0.x*y0.x + y0.y*y0.y + y0.z*y0.z + y0.w*y0.w
           + y1.x*y1.x + y1.y*y1.y + y1.z*y1.z + y1.w*y1.w;
  ss = warp_sum(ss) * (1.0f/DI);
  float inv = rsqrtf(ss + EPSF);
  const float4 w0 = *(const float4*)(nw + lane*4);
  const float4 w1 = *(const float4*)(nw + 256 + lane*4);
  y0.x *= inv*w0.x; y0.y *= inv*w0.y; y0.z *= inv*w0.z; y0.w *= inv*w0.w;
  y1.x *= inv*w1.x; y1.y *= inv*w1.y; y1.z *= inv*w1.z; y1.w *= inv*w1.w;
  *(float4*)(yr + lane*4) = y0;
  *(float4*)(yr + 256 + lane*4) = y1;
}

// ---------------- GEMMs ----------------

// A: qn (L x 256) gathered by ord; W: (256 x 1160); out split into gate / xbc / dt
__global__ __launch_bounds__(256) void gemm_in(const float* __restrict__ A, const float* __restrict__ W,
                                               const unsigned int* __restrict__ ord,
                                               float* __restrict__ gate, float* __restrict__ xbc,
                                               float* __restrict__ dtb) {
  __shared__ float As[64][36];
  __shared__ float Bs[32][64];
  int tid = threadIdx.x;
  int rb = blockIdx.y * 64, cb = blockIdx.x * 64;
  int tx = tid & 15, ty = tid >> 4;
  int lr = tid >> 3, lc = (tid & 7) * 4;
  int wr = tid >> 4, wc = (tid & 15) * 4;
  unsigned int src0 = ord[rb + lr];
  unsigned int src1 = ord[rb + lr + 32];
  float acc[4][4] = {};
  for (int k0 = 0; k0 < DM; k0 += 32) {
    float4 a0 = *(const float4*)(A + (size_t)src0*DM + k0 + lc);
    float4 a1 = *(const float4*)(A + (size_t)src1*DM + k0 + lc);
    *(float4*)&As[lr][lc] = a0;
    *(float4*)&As[lr+32][lc] = a1;
    #pragma unroll
    for (int rr = 0; rr < 2; ++rr) {
      int krow = k0 + wr + rr*16;
      #pragma unroll
      for (int e = 0; e < 4; ++e) {
        int col = cb + wc + e;
        Bs[wr + rr*16][wc+e] = (col < DP) ? W[(size_t)krow*DP + col] : 0.0f;
      }
    }
    __syncthreads();
    #pragma unroll
    for (int kk = 0; kk < 32; ++kk) {
      float av[4];
      #pragma unroll
      for (int i = 0; i < 4; ++i) av[i] = As[ty*4+i][kk];
      float4 b4 = *(const float4*)&Bs[kk][tx*4];
      float bv[4] = {b4.x, b4.y, b4.z, b4.w};
      #pragma unroll
      for (int i = 0; i < 4; ++i)
        #pragma unroll
        for (int j = 0; j < 4; ++j)
          acc[i][j] += av[i]*bv[j];
    }
    __syncthreads();
  }
  #pragma unroll
  for (int i = 0; i < 4; ++i) {
    int row = rb + ty*4 + i;
    #pragma unroll
    for (int j = 0; j < 4; ++j) {
      int col = cb + tx*4 + j;
      if (col < DP) {
        float v = acc[i][j];
        if (col < DI) gate[(size_t)row*DI + col] = v;
        else if (col < DI + CD) xbc[(size_t)row*CD + (col - DI)] = v;
        else dtb[(size_t)row*NH + (col - (DI + CD))] = v;
      }
    }
  }
}

// A: y (L x 512); W: (512 x 256); out[ord[row]*256 + col] += 0.5*acc
__global__ __launch_bounds__(256) void gemm_out(const float* __restrict__ A, const float* __restrict__ W,
                                                const unsigned int* __restrict__ ord, float* __restrict__ out) {
  __shared__ float As[64][36];
  __shared__ float Bs[32][64];
  int tid = threadIdx.x;
  int rb = blockIdx.y * 64, cb = blockIdx.x * 64;
  int tx = tid & 15, ty = tid >> 4;
  int lr = tid >> 3, lc = (tid & 7) * 4;
  int wr = tid >> 4, wc = (tid & 15) * 4;
  float acc[4][4] = {};
  for (int k0 = 0; k0 < DI; k0 += 32) {
    float4 a0 = *(const float4*)(A + (size_t)(rb+lr)*DI + k0 + lc);
    float4 a1 = *(const float4*)(A + (size_t)(rb+lr+32)*DI + k0 + lc);
    *(float4*)&As[lr][lc] = a0;
    *(float4*)&As[lr+32][lc] = a1;
    #pragma unroll
    for (int rr = 0; rr < 2; ++rr) {
      int krow = k0 + wr + rr*16;
      float4 b4 = *(const float4*)(W + (size_t)krow*DM + cb + wc);
      *(float4*)&Bs[wr + rr*16][wc] = b4;
    }
    __syncthreads();
    #pragma unroll
    for (int kk = 0; kk < 32; ++kk) {
      float av[4];
      #pragma unroll
      for (int i = 0; i < 4; ++i) av[i] = As[ty*4+i][kk];
      float4 b4 = *(const float4*)&Bs[kk][tx*4];
      float bv[4] = {b4.x, b4.y, b4.z, b4.w};
      #pragma unroll
      for (int i = 0; i < 4; ++i)
        #pragma unroll
        for (int j = 0; j < 4; ++j)
          acc[i][j] += av[i]*bv[j];
    }
    __syncthreads();
  }
  #pragma unroll
  for (int i = 0; i < 4; ++i) {
    int row = rb + ty*4 + i;
    unsigned int tok = ord[row];
    float* op = out + (size_t)tok*DM + cb + tx*4;
    float4 cur = *(float4*)op;
    cur.x += 0.5f*acc[i][0];
    cur.y += 0.5f*acc[i][1];
    cur.z += 0.5f*acc[i][2];
    cur.w += 0.5f*acc[i][3];
    *(float4*)op = cur;
  }
}

// ---------------- conv + dt ----------------

__global__ __launch_bounds__(256) void conv_kernel(const float* __restrict__ xbc, const float* __restrict__ cw,
                                                   const float* __restrict__ cbias, float* __restrict__ outc) {
  int idx = blockIdx.x*256 + threadIdx.x;
  if (idx >= L_TOK*CD) return;
  int c = idx % CD;
  int t = idx / CD;
  float s = cbias[c];
  #pragma unroll
  for (int kk = 0; kk < 4; ++kk) {
    int tt = t - 3 + kk;
    if (tt >= 0) s += cw[c*4+kk] * xbc[(size_t)tt*CD + c];
  }
  outc[idx] = siluf(s);
}

__global__ __launch_bounds__(256) void dt_kernel(float* __restrict__ dtb, const float* __restrict__ dt_bias) {
  int idx = blockIdx.x*256 + threadIdx.x;
  if (idx >= L_TOK*NH) return;
  float v = dtb[idx] + dt_bias[idx & 7];
  float sp = (v > 0.0f) ? (v + log1pf(expf(-v))) : log1pf(expf(v));
  dtb[idx] = sp;
}

// ---------------- chunked scan ----------------

// S_c[p][s] = sum_t exp(sum_{r>t} dt_r*A) * dt_t * x_t[p] * B_t[s];  P_c = exp(sum_t dt_t*A)
__global__ __launch_bounds__(256) void phaseA_kernel(const float* __restrict__ xc, const float* __restrict__ dtb,
                                                     const float* __restrict__ A_log,
                                                     float* __restrict__ S, float* __restrict__ P) {
  int c = blockIdx.x, h = blockIdx.y;
  int tid = threadIdx.x;
  __shared__ float xl[CHUNK][68];
  __shared__ float Bl[CHUNK][68];
  __shared__ float dts[CHUNK], lg[CHUNK], sfx[CHUNK], wgt[CHUNK];
  __shared__ float totals;
  int c0 = c*CHUNK;
  float Ah = -expf(A_log[h]);
  if (tid < CHUNK) {
    float dtv = dtb[(size_t)(c0+tid)*NH + h];
    dts[tid] = dtv;
    lg[tid] = dtv * Ah;
  }
  #pragma unroll
  for (int i = 0; i < 4; ++i) {
    int q = tid + 256*i;
    int t = q >> 4, cc = (q & 15)*4;
    float4 v = *(const float4*)(xc + (size_t)(c0+t)*CD + DI + cc);
    *(float4*)&Bl[t][cc] = v;
  }
  __syncthreads();
  if (tid == 0) {
    float run = 0.0f;
    for (int t = CHUNK-1; t >= 0; --t) { sfx[t] = run; run += lg[t]; }
    totals = run;
  }
  __syncthreads();
  if (tid < CHUNK) wgt[tid] = dts[tid] * expf(sfx[tid]);
  if (tid == 0) P[h*NC + c] = expf(totals);
  __syncthreads();
  #pragma unroll
  for (int i = 0; i < 4; ++i) {
    int q = tid + 256*i;
    int t = q >> 4, cc = (q & 15)*4;
    float4 v = *(const float4*)(xc + (size_t)(c0+t)*CD + h*HD + cc);
    float wv = wgt[t];
    v.x *= wv; v.y *= wv; v.z *= wv; v.w *= wv;
    *(float4*)&xl[t][cc] = v;
  }
  __syncthreads();
  int tx = tid & 15, ty = tid >> 4;
  float acc[4][4] = {};
  for (int t = 0; t < CHUNK; ++t) {
    float4 xv = *(const float4*)&xl[t][ty*4];
    float4 bv = *(const float4*)&Bl[t][tx*4];
    float xa[4] = {xv.x, xv.y, xv.z, xv.w};
    float ba[4] = {bv.x, bv.y, bv.z, bv.w};
    #pragma unroll
    for (int i = 0; i < 4; ++i)
      #pragma unroll
      for (int j = 0; j < 4; ++j)
        acc[i][j] += xa[i]*ba[j];
  }
  float* Sp = S + ((size_t)(h*NC + c))*4096;
  #pragma unroll
  for (int i = 0; i < 4; ++i) {
    float4 o = make_float4(acc[i][0], acc[i][1], acc[i][2], acc[i][3]);
    *(float4*)(Sp + (size_t)(ty*4+i)*64 + tx*4) = o;
  }
}

// sequential over chunks, elementwise-parallel; transforms S in place into h_start (state before chunk)
__global__ __launch_bounds__(256) void phaseB_kernel(float* __restrict__ S, const float* __restrict__ P) {
  int h = blockIdx.x >> 4;
  int e = (blockIdx.x & 15)*256 + threadIdx.x;
  size_t base = (size_t)h * NC * 4096 + e;
  const float* Ph = P + h*NC;
  float hs = 0.0f;
  float nxt = S[base];
  float Pn = Ph[0];
  for (int c = 0; c < NC; ++c) {
    float cur = nxt, Pc = Pn;
    if (c+1 < NC) { nxt = S[base + (size_t)(c+1)*4096]; Pn = Ph[c+1]; }
    S[base + (size_t)c*4096] = hs;
    hs = Pc*hs + cur;
  }
}

// Y_t[p] = sum_{s<=t} exp(pl[t]-pl[s])*dt_s*(C_t.B_s)*x_s[p] + exp(pl[t])*(C_t . h0[p]) + D_h*x_t[p]
__global__ __launch_bounds__(256) void phaseC_kernel(const float* __restrict__ xc, const float* __restrict__ dtb,
                                                     const float* __restrict__ A_log, const float* __restrict__ Dp,
                                                     const float* __restrict__ S, float* __restrict__ y) {
  int c = blockIdx.x, h = blockIdx.y, tid = threadIdx.x;
  __shared__ float Cl[CHUNK][68];    // [t][d]
  __shared__ float Bl[CHUNK][68];    // [s][d]
  __shared__ float xlT[HD][68];      // [p][t]
  __shared__ float h0[HD][68];       // [p][d]
  __shared__ float G[CHUNK][68];     // [t][s]
  __shared__ float dts[CHUNK], lg[CHUNK], pl[CHUNK], pe[CHUNK];
  int c0 = c*CHUNK;
  float Ah = -expf(A_log[h]);
  float Dh = Dp[h];
  if (tid < CHUNK) {
    float dtv = dtb[(size_t)(c0+tid)*NH + h];
    dts[tid] = dtv;
    lg[tid] = dtv*Ah;
  }
  const float* Sp = S + ((size_t)(h*NC + c))*4096;
  #pragma unroll
  for (int i = 0; i < 4; ++i) {
    int q = tid + 256*i;
    int t = q >> 4, cc = (q & 15)*4;
    float4 cv = *(const float4*)(xc + (size_t)(c0+t)*CD + DI + DS + cc);
    *(float4*)&Cl[t][cc] = cv;
    float4 bv = *(const float4*)(xc + (size_t)(c0+t)*CD + DI + cc);
    *(float4*)&Bl[t][cc] = bv;
    float4 xv = *(const float4*)(xc + (size_t)(c0+t)*CD + h*HD + cc);
    xlT[cc+0][t] = xv.x; xlT[cc+1][t] = xv.y; xlT[cc+2][t] = xv.z; xlT[cc+3][t] = xv.w;
    float4 hv = *(const float4*)(Sp + (size_t)t*64 + cc);   // t->p, cc->d
    *(float4*)&h0[t][cc] = hv;
  }
  __syncthreads();
  if (tid == 0) {
    float run = 0.0f;
    for (int t = 0; t < CHUNK; ++t) { run += lg[t]; pl[t] = run; }
  }
  __syncthreads();
  if (tid < CHUNK) pe[tid] = expf(pl[tid]);
  __syncthreads();
  int tx = tid & 15, ty = tid >> 4;
  // G phase: rows t = ty+16i, cols s = tx+16j
  {
    float acc[4][4] = {};
    for (int d = 0; d < DS; d += 4) {
      float4 cv[4], bv[4];
      #pragma unroll
      for (int i = 0; i < 4; ++i) cv[i] = *(const float4*)&Cl[ty + 16*i][d];
      #pragma unroll
      for (int j = 0; j < 4; ++j) bv[j] = *(const float4*)&Bl[tx + 16*j][d];
      #pragma unroll
      for (int i = 0; i < 4; ++i)
        #pragma unroll
        for (int j = 0; j < 4; ++j)
          acc[i][j] += dot4f(cv[i], bv[j]);
    }
    #pragma unroll
    for (int i = 0; i < 4; ++i) {
      int t = ty + 16*i;
      #pragma unroll
      for (int j = 0; j < 4; ++j) {
        int s = tx + 16*j;
        float v = 0.0f;
        if (s <= t) v = acc[i][j] * dts[s] * expf(pl[t] - pl[s]);
        G[t][s] = v;
      }
    }
  }
  __syncthreads();
  // Y phase
  {
    float acc[4][4] = {};
    for (int d = 0; d < DS; d += 4) {
      float4 cv[4], hv[4];
      #pragma unroll
      for (int i = 0; i < 4; ++i) cv[i] = *(const float4*)&Cl[ty + 16*i][d];
      #pragma unroll
      for (int j = 0; j < 4; ++j) hv[j] = *(const float4*)&h0[tx + 16*j][d];
      #pragma unroll
      for (int i = 0; i < 4; ++i)
        #pragma unroll
        for (int j = 0; j < 4; ++j)
          acc[i][j] += dot4f(cv[i], hv[j]);
    }
    #pragma unroll
    for (int i = 0; i < 4; ++i) {
      float sc = pe[ty + 16*i];
      #pragma unroll
      for (int j = 0; j < 4; ++j) acc[i][j] *= sc;
    }
    for (int s = 0; s < CHUNK; s += 4) {
      float4 gv[4], xv[4];
      #pragma unroll
      for (int i = 0; i < 4; ++i) gv[i] = *(const float4*)&G[ty + 16*i][s];
      #pragma unroll
      for (int j = 0; j < 4; ++j) xv[j] = *(const float4*)&xlT[tx + 16*j][s];
      #pragma unroll
      for (int i = 0; i < 4; ++i)
        #pragma unroll
        for (int j = 0; j < 4; ++j)
          acc[i][j] += dot4f(gv[i], xv[j]);
    }
    #pragma unroll
    for (int i = 0; i < 4; ++i) {
      int t = ty + 16*i;
      #pragma unroll
      for (int j = 0; j < 4; ++j) {
        int p = tx + 16*j;
        float v = acc[i][j] + Dh * xlT[p][t];
        y[(size_t)(c0+t)*DI + h*HD + p] = v;
      }
    }
  }
}

__global__ void fill_debug(float* out, float v) {
  int i = blockIdx.x*256 + threadIdx.x;
  if (i < L_TOK*DM) out[i] = v;
}

// ---------------- host ----------------

extern "C" void kernel_launch(void* const* d_in, const int* in_sizes, int n_in,
                              void* d_out, int out_size, void* d_ws, size_t ws_size,
                              hipStream_t stream) {
  const float* query = (const float*)d_in[0];
  const float* qpos  = (const float*)d_in[1];
  const float* pre_w = (const float*)d_in[2];
  const float* pre_b = (const float*)d_in[3];
  const float* fin_w = (const float*)d_in[4];
  const float* fin_b = (const float*)d_in[5];
  float* out = (float*)d_out;

  char* ws = (char*)d_ws;
  size_t off = 0;
  auto alloc = [&](size_t bytes) -> void* {
    void* p = ws + off;
    off += (bytes + 255) & ~(size_t)255;
    return p;
  };
  unsigned long long* keys = (unsigned long long*)alloc((size_t)2*L_TOK*8);
  unsigned int* ord = (unsigned int*)alloc((size_t)2*L_TOK*4);
  float* pmm  = (float*)alloc(256);
  float* qn   = (float*)alloc((size_t)L_TOK*DM*4);
  float* gate = (float*)alloc((size_t)L_TOK*DI*4);
  float* xbc  = (float*)alloc((size_t)L_TOK*CD*4);   // reused as y after conv
  float* convo= (float*)alloc((size_t)L_TOK*CD*4);
  float* dtb  = (float*)alloc((size_t)L_TOK*NH*4);
  float* Sbuf = (float*)alloc((size_t)NH*NC*4096*4);
  float* Pbuf = (float*)alloc((size_t)NH*NC*4);
  if (off > ws_size) {
    // debug channel: encode available ws MB into the output so the failure reports it
    fill_debug<<<(L_TOK*DM + 255)/256, 256, 0, stream>>>(out, (float)(ws_size >> 20));
    return;
  }

  minmax_kernel<<<1, 256, 0, stream>>>(qpos, pmm);
  hilbert_kernel<<<L_TOK/256, 256, 0, stream>>>(qpos, pmm, keys);
  sort_kernel<<<2, 1024, 0, stream>>>(keys, ord);
  hipMemcpyAsync(out, query, (size_t)L_TOK*DM*4, hipMemcpyDeviceToDevice, stream);

  for (int l = 0; l < 2; ++l) {
    int base = 6 + 8*l;
    const float* in_proj  = (const float*)d_in[base+0];
    const float* conv_w   = (const float*)d_in[base+1];
    const float* conv_b   = (const float*)d_in[base+2];
    const float* dt_bias  = (const float*)d_in[base+3];
    const float* A_log    = (const float*)d_in[base+4];
    const float* Dp       = (const float*)d_in[base+5];
    const float* norm_w   = (const float*)d_in[base+6];
    const float* out_proj = (const float*)d_in[base+7];

    ln_kernel<<<L_TOK/4, 256, 0, stream>>>(out, qn, pre_w, pre_b);
    for (int dir = 0; dir < 2; ++dir) {
      const unsigned int* o = ord + (size_t)dir*L_TOK;
      gemm_in<<<dim3((DP+63)/64, L_TOK/64), 256, 0, stream>>>(qn, in_proj, o, gate, xbc, dtb);
      conv_kernel<<<(L_TOK*CD)/256, 256, 0, stream>>>(xbc, conv_w, conv_b, convo);
      dt_kernel<<<(L_TOK*NH)/256, 256, 0, stream>>>(dtb, dt_bias);
      phaseA_kernel<<<dim3(NC, NH), 256, 0, stream>>>(convo, dtb, A_log, Sbuf, Pbuf);
      phaseB_kernel<<<128, 256, 0, stream>>>(Sbuf, Pbuf);
      phaseC_kernel<<<dim3(NC, NH), 256, 0, stream>>>(convo, dtb, A_log, Dp, Sbuf, xbc);
      gating_kernel<<<L_TOK/4, 256, 0, stream>>>(xbc, gate, norm_w);
      gemm_out<<<dim3(DM/64, L_TOK/64), 256, 0, stream>>>(xbc, out_proj, o, out);
    }
    ln_kernel<<<L_TOK/4, 256, 0, stream>>>(out, out, fin_w, fin_b);
  }
}

// Round 2
// 1961.364 us; speedup vs baseline: 1.3105x; 1.3105x over previous
//
#include <hip/hip_runtime.h>
#include <stdint.h>

#define L_TOK 16384
#define DM 256
#define DI 512
#define DS 64
#define NH 8
#define HD 64
#define CD 640
#define DP 1160
#define CHUNK 64
#define NC 256
#define EPSF 1e-5f

__device__ __forceinline__ float warp_sum(float v) {
  v += __shfl_xor(v, 1, 64);
  v += __shfl_xor(v, 2, 64);
  v += __shfl_xor(v, 4, 64);
  v += __shfl_xor(v, 8, 64);
  v += __shfl_xor(v, 16, 64);
  v += __shfl_xor(v, 32, 64);
  return v;
}

__device__ __forceinline__ float dot4f(const float4 a, const float4 b) {
  return a.x*b.x + a.y*b.y + a.z*b.z + a.w*b.w;
}

__device__ __forceinline__ float siluf(float x) { return x / (1.0f + expf(-x)); }

// ---------------- serialization ----------------

__global__ __launch_bounds__(256) void minmax_kernel(const float* __restrict__ pos, float* __restrict__ pmm) {
  __shared__ float sm[6][256];
  int tid = threadIdx.x;
  float mn0=1e30f, mn1=1e30f, mn2=1e30f, mx0=-1e30f, mx1=-1e30f, mx2=-1e30f;
  for (int t = tid; t < L_TOK; t += 256) {
    float a = pos[t*3+0], b = pos[t*3+1], c = pos[t*3+2];
    mn0=fminf(mn0,a); mx0=fmaxf(mx0,a);
    mn1=fminf(mn1,b); mx1=fmaxf(mx1,b);
    mn2=fminf(mn2,c); mx2=fmaxf(mx2,c);
  }
  sm[0][tid]=mn0; sm[1][tid]=mn1; sm[2][tid]=mn2;
  sm[3][tid]=mx0; sm[4][tid]=mx1; sm[5][tid]=mx2;
  __syncthreads();
  for (int s = 128; s > 0; s >>= 1) {
    if (tid < s) {
      #pragma unroll
      for (int d = 0; d < 3; ++d) {
        sm[d][tid]   = fminf(sm[d][tid],   sm[d][tid+s]);
        sm[3+d][tid] = fmaxf(sm[3+d][tid], sm[3+d][tid+s]);
      }
    }
    __syncthreads();
  }
  if (tid < 6) pmm[tid] = sm[tid][0];
}

__device__ unsigned int hilbert3(unsigned int a, unsigned int b, unsigned int c) {
  unsigned int x0 = a, x1 = b, x2 = c;
  for (unsigned int Q = 512u; Q > 1u; Q >>= 1) {
    unsigned int P = Q - 1u;
    // i = 0
    {
      if (x0 & Q) x0 ^= P;
    }
    // i = 1
    {
      unsigned int t = (x0 ^ x1) & P;
      if (x1 & Q) { x0 ^= P; }
      else { x0 ^= t; x1 ^= t; }
    }
    // i = 2
    {
      unsigned int t = (x0 ^ x2) & P;
      if (x2 & Q) { x0 ^= P; }
      else { x0 ^= t; x2 ^= t; }
    }
  }
  x1 ^= x0; x2 ^= x1;
  unsigned int tt = 0;
  for (unsigned int Q = 512u; Q > 1u; Q >>= 1)
    if (x2 & Q) tt ^= (Q - 1u);
  x0 ^= tt; x1 ^= tt; x2 ^= tt;
  unsigned int code = 0;
  #pragma unroll
  for (int bb = 9; bb >= 0; --bb) {
    code = (code << 1) | ((x0 >> bb) & 1u);
    code = (code << 1) | ((x1 >> bb) & 1u);
    code = (code << 1) | ((x2 >> bb) & 1u);
  }
  return code;
}

__global__ __launch_bounds__(256) void hilbert_kernel(const float* __restrict__ pos, const float* __restrict__ pmm,
                                                      unsigned long long* __restrict__ keys) {
  int t = blockIdx.x*256 + threadIdx.x;
  if (t >= L_TOK) return;
  unsigned int g[3];
  #pragma unroll
  for (int d = 0; d < 3; ++d) {
    float v = (pos[t*3+d] - pmm[d]) / (pmm[3+d] - pmm[d] + 1e-6f) * 1023.0f;
    v = fminf(fmaxf(v, 0.0f), 1023.0f);
    g[d] = (unsigned int)(int)v;
  }
  unsigned int ca = hilbert3(g[0], g[1], g[2]);
  unsigned int cb = hilbert3(g[1], g[0], g[2]);
  keys[t]         = ((unsigned long long)ca << 14) | (unsigned long long)t;
  keys[L_TOK + t] = ((unsigned long long)cb << 14) | (unsigned long long)t;
}

// all-pairs rank: rank[i] = #{j : key[j] < key[i]} over one 4096-key slice.
// keys unique (idx in low bits) => rank is exact stable-argsort position.
__global__ __launch_bounds__(256) void rank_partial(const unsigned long long* __restrict__ keys,
                                                    unsigned int* __restrict__ partial) {
  __shared__ unsigned long long tile[4096];
  int arr = blockIdx.y, ks = blockIdx.z;
  const unsigned long long* k = keys + (size_t)arr * L_TOK;
  int qi = blockIdx.x*256 + threadIdx.x;
  unsigned long long my = k[qi];
  const unsigned long long* src = k + ks*4096;
  #pragma unroll
  for (int t = 0; t < 16; ++t) tile[threadIdx.x + 256*t] = src[threadIdx.x + 256*t];
  __syncthreads();
  int r = 0;
  const ulonglong2* t2 = (const ulonglong2*)tile;
  #pragma unroll 8
  for (int j = 0; j < 2048; ++j) {
    ulonglong2 v = t2[j];
    r += (v.x < my) ? 1 : 0;
    r += (v.y < my) ? 1 : 0;
  }
  partial[(size_t)(ks*2 + arr)*L_TOK + qi] = (unsigned int)r;
}

__global__ __launch_bounds__(256) void rank_scatter(const unsigned long long* __restrict__ keys,
                                                    const unsigned int* __restrict__ partial,
                                                    unsigned int* __restrict__ ord) {
  int i = blockIdx.x*256 + threadIdx.x;   // 0 .. 2*L-1
  int arr = i >> 14;
  int qi = i & (L_TOK - 1);
  unsigned int r = 0;
  #pragma unroll
  for (int ks = 0; ks < 4; ++ks) r += partial[(size_t)(ks*2 + arr)*L_TOK + qi];
  ord[(size_t)arr*L_TOK + r] = (unsigned int)(keys[i] & 0x3FFFu);
}

// ---------------- layernorm / gating ----------------

__global__ __launch_bounds__(256) void ln_kernel(const float* __restrict__ in, float* __restrict__ out,
                                                 const float* __restrict__ w, const float* __restrict__ b) {
  int row = blockIdx.x*4 + (threadIdx.x >> 6);
  int lane = threadIdx.x & 63;
  const float4 v = *(const float4*)(in + (size_t)row*DM + lane*4);
  float s = v.x + v.y + v.z + v.w;
  float mean = warp_sum(s) * (1.0f/DM);
  float4 xc = make_float4(v.x-mean, v.y-mean, v.z-mean, v.w-mean);
  float ss = xc.x*xc.x + xc.y*xc.y + xc.z*xc.z + xc.w*xc.w;
  ss = warp_sum(ss) * (1.0f/DM);
  float inv = rsqrtf(ss + EPSF);
  const float4 w4 = *(const float4*)(w + lane*4);
  const float4 b4 = *(const float4*)(b + lane*4);
  float4 o;
  o.x = xc.x*inv*w4.x + b4.x;
  o.y = xc.y*inv*w4.y + b4.y;
  o.z = xc.z*inv*w4.z + b4.z;
  o.w = xc.w*inv*w4.w + b4.w;
  *(float4*)(out + (size_t)row*DM + lane*4) = o;
}

__global__ __launch_bounds__(256) void gating_kernel(float* __restrict__ y, const float* __restrict__ gate,
                                                     const float* __restrict__ nw) {
  int row = blockIdx.x*4 + (threadIdx.x >> 6);
  int lane = threadIdx.x & 63;
  float* yr = y + (size_t)row*DI;
  const float* gr = gate + (size_t)row*DI;
  float4 y0 = *(float4*)(yr + lane*4);
  float4 y1 = *(float4*)(yr + 256 + lane*4);
  const float4 g0 = *(const float4*)(gr + lane*4);
  const float4 g1 = *(const float4*)(gr + 256 + lane*4);
  y0.x *= siluf(g0.x); y0.y *= siluf(g0.y); y0.z *= siluf(g0.z); y0.w *= siluf(g0.w);
  y1.x *= siluf(g1.x); y1.y *= siluf(g1.y); y1.z *= siluf(g1.z); y1.w *= siluf(g1.w);
  float ss = y0.x*y0.x + y0.y*y0.y + y0.z*y0.z + y0.w*y0.w
           + y1.x*y1.x + y1.y*y1.y + y1.z*y1.z + y1.w*y1.w;
  ss = warp_sum(ss) * (1.0f/DI);
  float inv = rsqrtf(ss + EPSF);
  const float4 w0 = *(const float4*)(nw + lane*4);
  const float4 w1 = *(const float4*)(nw + 256 + lane*4);
  y0.x *= inv*w0.x; y0.y *= inv*w0.y; y0.z *= inv*w0.z; y0.w *= inv*w0.w;
  y1.x *= inv*w1.x; y1.y *= inv*w1.y; y1.z *= inv*w1.z; y1.w *= inv*w1.w;
  *(float4*)(yr + lane*4) = y0;
  *(float4*)(yr + 256 + lane*4) = y1;
}

// ---------------- GEMMs ----------------

// A: qn (L x 256) gathered by ord; W: (256 x 1160); out split into gate / xbc / dt
__global__ __launch_bounds__(256) void gemm_in(const float* __restrict__ A, const float* __restrict__ W,
                                               const unsigned int* __restrict__ ord,
                                               float* __restrict__ gate, float* __restrict__ xbc,
                                               float* __restrict__ dtb) {
  __shared__ float As[64][36];
  __shared__ float Bs[32][64];
  int tid = threadIdx.x;
  int rb = blockIdx.y * 64, cb = blockIdx.x * 64;
  int tx = tid & 15, ty = tid >> 4;
  int lr = tid >> 3, lc = (tid & 7) * 4;
  int wr = tid >> 4, wc = (tid & 15) * 4;
  unsigned int src0 = ord[rb + lr];
  unsigned int src1 = ord[rb + lr + 32];
  float acc[4][4] = {};
  for (int k0 = 0; k0 < DM; k0 += 32) {
    float4 a0 = *(const float4*)(A + (size_t)src0*DM + k0 + lc);
    float4 a1 = *(const float4*)(A + (size_t)src1*DM + k0 + lc);
    *(float4*)&As[lr][lc] = a0;
    *(float4*)&As[lr+32][lc] = a1;
    #pragma unroll
    for (int rr = 0; rr < 2; ++rr) {
      int krow = k0 + wr + rr*16;
      #pragma unroll
      for (int e = 0; e < 4; ++e) {
        int col = cb + wc + e;
        Bs[wr + rr*16][wc+e] = (col < DP) ? W[(size_t)krow*DP + col] : 0.0f;
      }
    }
    __syncthreads();
    #pragma unroll
    for (int kk = 0; kk < 32; ++kk) {
      float av[4];
      #pragma unroll
      for (int i = 0; i < 4; ++i) av[i] = As[ty*4+i][kk];
      float4 b4 = *(const float4*)&Bs[kk][tx*4];
      float bv[4] = {b4.x, b4.y, b4.z, b4.w};
      #pragma unroll
      for (int i = 0; i < 4; ++i)
        #pragma unroll
        for (int j = 0; j < 4; ++j)
          acc[i][j] += av[i]*bv[j];
    }
    __syncthreads();
  }
  #pragma unroll
  for (int i = 0; i < 4; ++i) {
    int row = rb + ty*4 + i;
    #pragma unroll
    for (int j = 0; j < 4; ++j) {
      int col = cb + tx*4 + j;
      if (col < DP) {
        float v = acc[i][j];
        if (col < DI) gate[(size_t)row*DI + col] = v;
        else if (col < DI + CD) xbc[(size_t)row*CD + (col - DI)] = v;
        else dtb[(size_t)row*NH + (col - (DI + CD))] = v;
      }
    }
  }
}

// A: y (L x 512); W: (512 x 256); out[ord[row]*256 + col] += 0.5*acc
__global__ __launch_bounds__(256) void gemm_out(const float* __restrict__ A, const float* __restrict__ W,
                                                const unsigned int* __restrict__ ord, float* __restrict__ out) {
  __shared__ float As[64][36];
  __shared__ float Bs[32][64];
  int tid = threadIdx.x;
  int rb = blockIdx.y * 64, cb = blockIdx.x * 64;
  int tx = tid & 15, ty = tid >> 4;
  int lr = tid >> 3, lc = (tid & 7) * 4;
  int wr = tid >> 4, wc = (tid & 15) * 4;
  float acc[4][4] = {};
  for (int k0 = 0; k0 < DI; k0 += 32) {
    float4 a0 = *(const float4*)(A + (size_t)(rb+lr)*DI + k0 + lc);
    float4 a1 = *(const float4*)(A + (size_t)(rb+lr+32)*DI + k0 + lc);
    *(float4*)&As[lr][lc] = a0;
    *(float4*)&As[lr+32][lc] = a1;
    #pragma unroll
    for (int rr = 0; rr < 2; ++rr) {
      int krow = k0 + wr + rr*16;
      float4 b4 = *(const float4*)(W + (size_t)krow*DM + cb + wc);
      *(float4*)&Bs[wr + rr*16][wc] = b4;
    }
    __syncthreads();
    #pragma unroll
    for (int kk = 0; kk < 32; ++kk) {
      float av[4];
      #pragma unroll
      for (int i = 0; i < 4; ++i) av[i] = As[ty*4+i][kk];
      float4 b4 = *(const float4*)&Bs[kk][tx*4];
      float bv[4] = {b4.x, b4.y, b4.z, b4.w};
      #pragma unroll
      for (int i = 0; i < 4; ++i)
        #pragma unroll
        for (int j = 0; j < 4; ++j)
          acc[i][j] += av[i]*bv[j];
    }
    __syncthreads();
  }
  #pragma unroll
  for (int i = 0; i < 4; ++i) {
    int row = rb + ty*4 + i;
    unsigned int tok = ord[row];
    float* op = out + (size_t)tok*DM + cb + tx*4;
    float4 cur = *(float4*)op;
    cur.x += 0.5f*acc[i][0];
    cur.y += 0.5f*acc[i][1];
    cur.z += 0.5f*acc[i][2];
    cur.w += 0.5f*acc[i][3];
    *(float4*)op = cur;
  }
}

// ---------------- conv + dt ----------------

__global__ __launch_bounds__(256) void conv_kernel(const float* __restrict__ xbc, const float* __restrict__ cw,
                                                   const float* __restrict__ cbias, float* __restrict__ outc) {
  int idx = blockIdx.x*256 + threadIdx.x;
  if (idx >= L_TOK*CD) return;
  int c = idx % CD;
  int t = idx / CD;
  float s = cbias[c];
  #pragma unroll
  for (int kk = 0; kk < 4; ++kk) {
    int tt = t - 3 + kk;
    if (tt >= 0) s += cw[c*4+kk] * xbc[(size_t)tt*CD + c];
  }
  outc[idx] = siluf(s);
}

__global__ __launch_bounds__(256) void dt_kernel(float* __restrict__ dtb, const float* __restrict__ dt_bias) {
  int idx = blockIdx.x*256 + threadIdx.x;
  if (idx >= L_TOK*NH) return;
  float v = dtb[idx] + dt_bias[idx & 7];
  float sp = (v > 0.0f) ? (v + log1pf(expf(-v))) : log1pf(expf(v));
  dtb[idx] = sp;
}

// ---------------- chunked scan ----------------

// S_c[p][s] = sum_t exp(sum_{r>t} dt_r*A) * dt_t * x_t[p] * B_t[s];  P_c = exp(sum_t dt_t*A)
__global__ __launch_bounds__(256) void phaseA_kernel(const float* __restrict__ xc, const float* __restrict__ dtb,
                                                     const float* __restrict__ A_log,
                                                     float* __restrict__ S, float* __restrict__ P) {
  int c = blockIdx.x, h = blockIdx.y;
  int tid = threadIdx.x;
  __shared__ float xl[CHUNK][68];
  __shared__ float Bl[CHUNK][68];
  __shared__ float dts[CHUNK], lg[CHUNK], sfx[CHUNK], wgt[CHUNK];
  __shared__ float totals;
  int c0 = c*CHUNK;
  float Ah = -expf(A_log[h]);
  if (tid < CHUNK) {
    float dtv = dtb[(size_t)(c0+tid)*NH + h];
    dts[tid] = dtv;
    lg[tid] = dtv * Ah;
  }
  #pragma unroll
  for (int i = 0; i < 4; ++i) {
    int q = tid + 256*i;
    int t = q >> 4, cc = (q & 15)*4;
    float4 v = *(const float4*)(xc + (size_t)(c0+t)*CD + DI + cc);
    *(float4*)&Bl[t][cc] = v;
  }
  __syncthreads();
  if (tid == 0) {
    float run = 0.0f;
    for (int t = CHUNK-1; t >= 0; --t) { sfx[t] = run; run += lg[t]; }
    totals = run;
  }
  __syncthreads();
  if (tid < CHUNK) wgt[tid] = dts[tid] * expf(sfx[tid]);
  if (tid == 0) P[h*NC + c] = expf(totals);
  __syncthreads();
  #pragma unroll
  for (int i = 0; i < 4; ++i) {
    int q = tid + 256*i;
    int t = q >> 4, cc = (q & 15)*4;
    float4 v = *(const float4*)(xc + (size_t)(c0+t)*CD + h*HD + cc);
    float wv = wgt[t];
    v.x *= wv; v.y *= wv; v.z *= wv; v.w *= wv;
    *(float4*)&xl[t][cc] = v;
  }
  __syncthreads();
  int tx = tid & 15, ty = tid >> 4;
  float acc[4][4] = {};
  for (int t = 0; t < CHUNK; ++t) {
    float4 xv = *(const float4*)&xl[t][ty*4];
    float4 bv = *(const float4*)&Bl[t][tx*4];
    float xa[4] = {xv.x, xv.y, xv.z, xv.w};
    float ba[4] = {bv.x, bv.y, bv.z, bv.w};
    #pragma unroll
    for (int i = 0; i < 4; ++i)
      #pragma unroll
      for (int j = 0; j < 4; ++j)
        acc[i][j] += xa[i]*ba[j];
  }
  float* Sp = S + ((size_t)(h*NC + c))*4096;
  #pragma unroll
  for (int i = 0; i < 4; ++i) {
    float4 o = make_float4(acc[i][0], acc[i][1], acc[i][2], acc[i][3]);
    *(float4*)(Sp + (size_t)(ty*4+i)*64 + tx*4) = o;
  }
}

// sequential over chunks, elementwise-parallel; transforms S in place into h_start (state before chunk).
// Double-buffered groups of 4 -> 4 outstanding loads, overlap with compute+stores.
__global__ __launch_bounds__(256) void phaseB_kernel(float* __restrict__ S, const float* __restrict__ P) {
  int h = blockIdx.x >> 4;
  int e = (blockIdx.x & 15)*256 + threadIdx.x;
  size_t base = (size_t)h * NC * 4096 + e;
  const float* Ph = P + h*NC;
  float hs = 0.0f;
  float buf[4], nbuf[4];
  #pragma unroll
  for (int k = 0; k < 4; ++k) buf[k] = S[base + (size_t)k*4096];
  for (int c = 0; c < NC; c += 4) {
    if (c + 4 < NC) {
      #pragma unroll
      for (int k = 0; k < 4; ++k) nbuf[k] = S[base + (size_t)(c+4+k)*4096];
    }
    #pragma unroll
    for (int k = 0; k < 4; ++k) {
      S[base + (size_t)(c+k)*4096] = hs;
      hs = Ph[c+k]*hs + buf[k];
    }
    #pragma unroll
    for (int k = 0; k < 4; ++k) buf[k] = nbuf[k];
  }
}

// Y_t[p] = sum_{s<=t} exp(pl[t]-pl[s])*dt_s*(C_t.B_s)*x_s[p] + exp(pl[t])*(C_t . h0[p]) + D_h*x_t[p]
__global__ __launch_bounds__(256) void phaseC_kernel(const float* __restrict__ xc, const float* __restrict__ dtb,
                                                     const float* __restrict__ A_log, const float* __restrict__ Dp,
                                                     const float* __restrict__ S, float* __restrict__ y) {
  int c = blockIdx.x, h = blockIdx.y, tid = threadIdx.x;
  __shared__ float Cl[CHUNK][68];    // [t][d]
  __shared__ float Bl[CHUNK][68];    // [s][d]
  __shared__ float xlT[HD][68];      // [p][t]
  __shared__ float h0[HD][68];       // [p][d]
  __shared__ float G[CHUNK][68];     // [t][s]
  __shared__ float dts[CHUNK], lg[CHUNK], pl[CHUNK], pe[CHUNK];
  int c0 = c*CHUNK;
  float Ah = -expf(A_log[h]);
  float Dh = Dp[h];
  if (tid < CHUNK) {
    float dtv = dtb[(size_t)(c0+tid)*NH + h];
    dts[tid] = dtv;
    lg[tid] = dtv*Ah;
  }
  const float* Sp = S + ((size_t)(h*NC + c))*4096;
  #pragma unroll
  for (int i = 0; i < 4; ++i) {
    int q = tid + 256*i;
    int t = q >> 4, cc = (q & 15)*4;
    float4 cv = *(const float4*)(xc + (size_t)(c0+t)*CD + DI + DS + cc);
    *(float4*)&Cl[t][cc] = cv;
    float4 bv = *(const float4*)(xc + (size_t)(c0+t)*CD + DI + cc);
    *(float4*)&Bl[t][cc] = bv;
    float4 xv = *(const float4*)(xc + (size_t)(c0+t)*CD + h*HD + cc);
    xlT[cc+0][t] = xv.x; xlT[cc+1][t] = xv.y; xlT[cc+2][t] = xv.z; xlT[cc+3][t] = xv.w;
    float4 hv = *(const float4*)(Sp + (size_t)t*64 + cc);   // t->p, cc->d
    *(float4*)&h0[t][cc] = hv;
  }
  __syncthreads();
  if (tid == 0) {
    float run = 0.0f;
    for (int t = 0; t < CHUNK; ++t) { run += lg[t]; pl[t] = run; }
  }
  __syncthreads();
  if (tid < CHUNK) pe[tid] = expf(pl[tid]);
  __syncthreads();
  int tx = tid & 15, ty = tid >> 4;
  // G phase: rows t = ty+16i, cols s = tx+16j
  {
    float acc[4][4] = {};
    for (int d = 0; d < DS; d += 4) {
      float4 cv[4], bv[4];
      #pragma unroll
      for (int i = 0; i < 4; ++i) cv[i] = *(const float4*)&Cl[ty + 16*i][d];
      #pragma unroll
      for (int j = 0; j < 4; ++j) bv[j] = *(const float4*)&Bl[tx + 16*j][d];
      #pragma unroll
      for (int i = 0; i < 4; ++i)
        #pragma unroll
        for (int j = 0; j < 4; ++j)
          acc[i][j] += dot4f(cv[i], bv[j]);
    }
    #pragma unroll
    for (int i = 0; i < 4; ++i) {
      int t = ty + 16*i;
      #pragma unroll
      for (int j = 0; j < 4; ++j) {
        int s = tx + 16*j;
        float v = 0.0f;
        if (s <= t) v = acc[i][j] * dts[s] * expf(pl[t] - pl[s]);
        G[t][s] = v;
      }
    }
  }
  __syncthreads();
  // Y phase
  {
    float acc[4][4] = {};
    for (int d = 0; d < DS; d += 4) {
      float4 cv[4], hv[4];
      #pragma unroll
      for (int i = 0; i < 4; ++i) cv[i] = *(const float4*)&Cl[ty + 16*i][d];
      #pragma unroll
      for (int j = 0; j < 4; ++j) hv[j] = *(const float4*)&h0[tx + 16*j][d];
      #pragma unroll
      for (int i = 0; i < 4; ++i)
        #pragma unroll
        for (int j = 0; j < 4; ++j)
          acc[i][j] += dot4f(cv[i], hv[j]);
    }
    #pragma unroll
    for (int i = 0; i < 4; ++i) {
      float sc = pe[ty + 16*i];
      #pragma unroll
      for (int j = 0; j < 4; ++j) acc[i][j] *= sc;
    }
    for (int s = 0; s < CHUNK; s += 4) {
      float4 gv[4], xv[4];
      #pragma unroll
      for (int i = 0; i < 4; ++i) gv[i] = *(const float4*)&G[ty + 16*i][s];
      #pragma unroll
      for (int j = 0; j < 4; ++j) xv[j] = *(const float4*)&xlT[tx + 16*j][s];
      #pragma unroll
      for (int i = 0; i < 4; ++i)
        #pragma unroll
        for (int j = 0; j < 4; ++j)
          acc[i][j] += dot4f(gv[i], xv[j]);
    }
    #pragma unroll
    for (int i = 0; i < 4; ++i) {
      int t = ty + 16*i;
      #pragma unroll
      for (int j = 0; j < 4; ++j) {
        int p = tx + 16*j;
        float v = acc[i][j] + Dh * xlT[p][t];
        y[(size_t)(c0+t)*DI + h*HD + p] = v;
      }
    }
  }
}

__global__ void fill_debug(float* out, float v) {
  int i = blockIdx.x*256 + threadIdx.x;
  if (i < L_TOK*DM) out[i] = v;
}

// ---------------- host ----------------

extern "C" void kernel_launch(void* const* d_in, const int* in_sizes, int n_in,
                              void* d_out, int out_size, void* d_ws, size_t ws_size,
                              hipStream_t stream) {
  const float* query = (const float*)d_in[0];
  const float* qpos  = (const float*)d_in[1];
  const float* pre_w = (const float*)d_in[2];
  const float* pre_b = (const float*)d_in[3];
  const float* fin_w = (const float*)d_in[4];
  const float* fin_b = (const float*)d_in[5];
  float* out = (float*)d_out;

  char* ws = (char*)d_ws;
  size_t off = 0;
  auto alloc = [&](size_t bytes) -> void* {
    void* p = ws + off;
    off += (bytes + 255) & ~(size_t)255;
    return p;
  };
  unsigned long long* keys = (unsigned long long*)alloc((size_t)2*L_TOK*8);
  unsigned int* ord = (unsigned int*)alloc((size_t)2*L_TOK*4);
  unsigned int* rpart = (unsigned int*)alloc((size_t)4*2*L_TOK*4);
  float* pmm  = (float*)alloc(256);
  float* qn   = (float*)alloc((size_t)L_TOK*DM*4);
  float* gate = (float*)alloc((size_t)L_TOK*DI*4);
  float* xbc  = (float*)alloc((size_t)L_TOK*CD*4);   // reused as y after conv
  float* convo= (float*)alloc((size_t)L_TOK*CD*4);
  float* dtb  = (float*)alloc((size_t)L_TOK*NH*4);
  float* Sbuf = (float*)alloc((size_t)NH*NC*4096*4);
  float* Pbuf = (float*)alloc((size_t)NH*NC*4);
  if (off > ws_size) {
    // debug channel: encode available ws MB into the output so the failure reports it
    fill_debug<<<(L_TOK*DM + 255)/256, 256, 0, stream>>>(out, (float)(ws_size >> 20));
    return;
  }

  minmax_kernel<<<1, 256, 0, stream>>>(qpos, pmm);
  hilbert_kernel<<<L_TOK/256, 256, 0, stream>>>(qpos, pmm, keys);
  rank_partial<<<dim3(L_TOK/256, 2, 4), 256, 0, stream>>>(keys, rpart);
  rank_scatter<<<(2*L_TOK)/256, 256, 0, stream>>>(keys, rpart, ord);
  hipMemcpyAsync(out, query, (size_t)L_TOK*DM*4, hipMemcpyDeviceToDevice, stream);

  for (int l = 0; l < 2; ++l) {
    int base = 6 + 8*l;
    const float* in_proj  = (const float*)d_in[base+0];
    const float* conv_w   = (const float*)d_in[base+1];
    const float* conv_b   = (const float*)d_in[base+2];
    const float* dt_bias  = (const float*)d_in[base+3];
    const float* A_log    = (const float*)d_in[base+4];
    const float* Dp       = (const float*)d_in[base+5];
    const float* norm_w   = (const float*)d_in[base+6];
    const float* out_proj = (const float*)d_in[base+7];

    ln_kernel<<<L_TOK/4, 256, 0, stream>>>(out, qn, pre_w, pre_b);
    for (int dir = 0; dir < 2; ++dir) {
      const unsigned int* o = ord + (size_t)dir*L_TOK;
      gemm_in<<<dim3((DP+63)/64, L_TOK/64), 256, 0, stream>>>(qn, in_proj, o, gate, xbc, dtb);
      conv_kernel<<<(L_TOK*CD)/256, 256, 0, stream>>>(xbc, conv_w, conv_b, convo);
      dt_kernel<<<(L_TOK*NH)/256, 256, 0, stream>>>(dtb, dt_bias);
      phaseA_kernel<<<dim3(NC, NH), 256, 0, stream>>>(convo, dtb, A_log, Sbuf, Pbuf);
      phaseB_kernel<<<128, 256, 0, stream>>>(Sbuf, Pbuf);
      phaseC_kernel<<<dim3(NC, NH), 256, 0, stream>>>(convo, dtb, A_log, Dp, Sbuf, xbc);
      gating_kernel<<<L_TOK/4, 256, 0, stream>>>(xbc, gate, norm_w);
      gemm_out<<<dim3(DM/64, L_TOK/64), 256, 0, stream>>>(xbc, out_proj, o, out);
    }
    ln_kernel<<<L_TOK/4, 256, 0, stream>>>(out, out, fin_w, fin_b);
  }
}

// Round 3
// 1303.399 us; speedup vs baseline: 1.9720x; 1.5048x over previous
//
#include <hip/hip_runtime.h>
#include <stdint.h>

#define L_TOK 16384
#define DM 256
#define DI 512
#define DS 64
#define NH 8
#define HD 64
#define CD 640
#define DP 1160
#define CHUNK 64
#define NC 256
#define EPSF 1e-5f

typedef __attribute__((ext_vector_type(8))) short short8;
typedef __attribute__((ext_vector_type(4))) float f32x4;

#define GLL16(gp, lp) __builtin_amdgcn_global_load_lds((const __attribute__((address_space(1))) void*)(gp), (__attribute__((address_space(3))) void*)(lp), 16, 0, 0)

__device__ __forceinline__ float warp_sum(float v) {
  v += __shfl_xor(v, 1, 64);
  v += __shfl_xor(v, 2, 64);
  v += __shfl_xor(v, 4, 64);
  v += __shfl_xor(v, 8, 64);
  v += __shfl_xor(v, 16, 64);
  v += __shfl_xor(v, 32, 64);
  return v;
}

__device__ __forceinline__ float dot4f(const float4 a, const float4 b) {
  return a.x*b.x + a.y*b.y + a.z*b.z + a.w*b.w;
}

__device__ __forceinline__ float siluf(float x) { return x / (1.0f + expf(-x)); }

// round-to-nearest-even f32 -> bf16
__device__ __forceinline__ unsigned short f2bf(float f) {
  unsigned int u = __float_as_uint(f);
  unsigned int r = (u + 0x7FFFu + ((u >> 16) & 1u)) >> 16;
  return (unsigned short)r;
}

// ---------------- serialization ----------------

__global__ __launch_bounds__(256) void minmax_kernel(const float* __restrict__ pos, float* __restrict__ pmm) {
  __shared__ float sm[6][256];
  int tid = threadIdx.x;
  float mn0=1e30f, mn1=1e30f, mn2=1e30f, mx0=-1e30f, mx1=-1e30f, mx2=-1e30f;
  for (int t = tid; t < L_TOK; t += 256) {
    float a = pos[t*3+0], b = pos[t*3+1], c = pos[t*3+2];
    mn0=fminf(mn0,a); mx0=fmaxf(mx0,a);
    mn1=fminf(mn1,b); mx1=fmaxf(mx1,b);
    mn2=fminf(mn2,c); mx2=fmaxf(mx2,c);
  }
  sm[0][tid]=mn0; sm[1][tid]=mn1; sm[2][tid]=mn2;
  sm[3][tid]=mx0; sm[4][tid]=mx1; sm[5][tid]=mx2;
  __syncthreads();
  for (int s = 128; s > 0; s >>= 1) {
    if (tid < s) {
      #pragma unroll
      for (int d = 0; d < 3; ++d) {
        sm[d][tid]   = fminf(sm[d][tid],   sm[d][tid+s]);
        sm[3+d][tid] = fmaxf(sm[3+d][tid], sm[3+d][tid+s]);
      }
    }
    __syncthreads();
  }
  if (tid < 6) pmm[tid] = sm[tid][0];
}

__device__ unsigned int hilbert3(unsigned int a, unsigned int b, unsigned int c) {
  unsigned int x0 = a, x1 = b, x2 = c;
  for (unsigned int Q = 512u; Q > 1u; Q >>= 1) {
    unsigned int P = Q - 1u;
    { if (x0 & Q) x0 ^= P; }
    {
      unsigned int t = (x0 ^ x1) & P;
      if (x1 & Q) { x0 ^= P; }
      else { x0 ^= t; x1 ^= t; }
    }
    {
      unsigned int t = (x0 ^ x2) & P;
      if (x2 & Q) { x0 ^= P; }
      else { x0 ^= t; x2 ^= t; }
    }
  }
  x1 ^= x0; x2 ^= x1;
  unsigned int tt = 0;
  for (unsigned int Q = 512u; Q > 1u; Q >>= 1)
    if (x2 & Q) tt ^= (Q - 1u);
  x0 ^= tt; x1 ^= tt; x2 ^= tt;
  unsigned int code = 0;
  #pragma unroll
  for (int bb = 9; bb >= 0; --bb) {
    code = (code << 1) | ((x0 >> bb) & 1u);
    code = (code << 1) | ((x1 >> bb) & 1u);
    code = (code << 1) | ((x2 >> bb) & 1u);
  }
  return code;
}

__global__ __launch_bounds__(256) void hilbert_kernel(const float* __restrict__ pos, const float* __restrict__ pmm,
                                                      unsigned long long* __restrict__ keys) {
  int t = blockIdx.x*256 + threadIdx.x;
  if (t >= L_TOK) return;
  unsigned int g[3];
  #pragma unroll
  for (int d = 0; d < 3; ++d) {
    float v = (pos[t*3+d] - pmm[d]) / (pmm[3+d] - pmm[d] + 1e-6f) * 1023.0f;
    v = fminf(fmaxf(v, 0.0f), 1023.0f);
    g[d] = (unsigned int)(int)v;
  }
  unsigned int ca = hilbert3(g[0], g[1], g[2]);
  unsigned int cb = hilbert3(g[1], g[0], g[2]);
  keys[t]         = ((unsigned long long)ca << 14) | (unsigned long long)t;
  keys[L_TOK + t] = ((unsigned long long)cb << 14) | (unsigned long long)t;
}

__global__ __launch_bounds__(256) void rank_partial(const unsigned long long* __restrict__ keys,
                                                    unsigned int* __restrict__ partial) {
  __shared__ unsigned long long tile[4096];
  int arr = blockIdx.y, ks = blockIdx.z;
  const unsigned long long* k = keys + (size_t)arr * L_TOK;
  int qi = blockIdx.x*256 + threadIdx.x;
  unsigned long long my = k[qi];
  const unsigned long long* src = k + ks*4096;
  #pragma unroll
  for (int t = 0; t < 16; ++t) tile[threadIdx.x + 256*t] = src[threadIdx.x + 256*t];
  __syncthreads();
  int r = 0;
  const ulonglong2* t2 = (const ulonglong2*)tile;
  #pragma unroll 8
  for (int j = 0; j < 2048; ++j) {
    ulonglong2 v = t2[j];
    r += (v.x < my) ? 1 : 0;
    r += (v.y < my) ? 1 : 0;
  }
  partial[(size_t)(ks*2 + arr)*L_TOK + qi] = (unsigned int)r;
}

__global__ __launch_bounds__(256) void rank_scatter(const unsigned long long* __restrict__ keys,
                                                    const unsigned int* __restrict__ partial,
                                                    unsigned int* __restrict__ ord) {
  int i = blockIdx.x*256 + threadIdx.x;
  int arr = i >> 14;
  int qi = i & (L_TOK - 1);
  unsigned int r = 0;
  #pragma unroll
  for (int ks = 0; ks < 4; ++ks) r += partial[(size_t)(ks*2 + arr)*L_TOK + qi];
  ord[(size_t)arr*L_TOK + r] = (unsigned int)(keys[i] & 0x3FFFu);
}

// ---------------- layernorm / gating ----------------

// writes fp32 out; optionally also bf16 copy (for MFMA A-operand)
__global__ __launch_bounds__(256) void ln_kernel(const float* __restrict__ in, float* __restrict__ out,
                                                 unsigned short* __restrict__ outbf,
                                                 const float* __restrict__ w, const float* __restrict__ b) {
  int row = blockIdx.x*4 + (threadIdx.x >> 6);
  int lane = threadIdx.x & 63;
  const float4 v = *(const float4*)(in + (size_t)row*DM + lane*4);
  float s = v.x + v.y + v.z + v.w;
  float mean = warp_sum(s) * (1.0f/DM);
  float4 xc = make_float4(v.x-mean, v.y-mean, v.z-mean, v.w-mean);
  float ss = xc.x*xc.x + xc.y*xc.y + xc.z*xc.z + xc.w*xc.w;
  ss = warp_sum(ss) * (1.0f/DM);
  float inv = rsqrtf(ss + EPSF);
  const float4 w4 = *(const float4*)(w + lane*4);
  const float4 b4 = *(const float4*)(b + lane*4);
  float4 o;
  o.x = xc.x*inv*w4.x + b4.x;
  o.y = xc.y*inv*w4.y + b4.y;
  o.z = xc.z*inv*w4.z + b4.z;
  o.w = xc.w*inv*w4.w + b4.w;
  *(float4*)(out + (size_t)row*DM + lane*4) = o;
  if (outbf) {
    ushort4 ob = make_ushort4(f2bf(o.x), f2bf(o.y), f2bf(o.z), f2bf(o.w));
    *(ushort4*)(outbf + (size_t)row*DM + lane*4) = ob;
  }
}

// y(fp32, from phaseC in xbc buf) * silu(gate) -> rmsnorm*w -> bf16 out
__global__ __launch_bounds__(256) void gating_kernel(const float* __restrict__ y, const float* __restrict__ gate,
                                                     const float* __restrict__ nw, unsigned short* __restrict__ ybf) {
  int row = blockIdx.x*4 + (threadIdx.x >> 6);
  int lane = threadIdx.x & 63;
  const float* yr = y + (size_t)row*DI;
  const float* gr = gate + (size_t)row*DI;
  float4 y0 = *(const float4*)(yr + lane*4);
  float4 y1 = *(const float4*)(yr + 256 + lane*4);
  const float4 g0 = *(const float4*)(gr + lane*4);
  const float4 g1 = *(const float4*)(gr + 256 + lane*4);
  y0.x *= siluf(g0.x); y0.y *= siluf(g0.y); y0.z *= siluf(g0.z); y0.w *= siluf(g0.w);
  y1.x *= siluf(g1.x); y1.y *= siluf(g1.y); y1.z *= siluf(g1.z); y1.w *= siluf(g1.w);
  float ss = y0.x*y0.x + y0.y*y0.y + y0.z*y0.z + y0.w*y0.w
           + y1.x*y1.x + y1.y*y1.y + y1.z*y1.z + y1.w*y1.w;
  ss = warp_sum(ss) * (1.0f/DI);
  float inv = rsqrtf(ss + EPSF);
  const float4 w0 = *(const float4*)(nw + lane*4);
  const float4 w1 = *(const float4*)(nw + 256 + lane*4);
  y0.x *= inv*w0.x; y0.y *= inv*w0.y; y0.z *= inv*w0.z; y0.w *= inv*w0.w;
  y1.x *= inv*w1.x; y1.y *= inv*w1.y; y1.z *= inv*w1.z; y1.w *= inv*w1.w;
  *(ushort4*)(ybf + (size_t)row*DI + lane*4)       = make_ushort4(f2bf(y0.x), f2bf(y0.y), f2bf(y0.z), f2bf(y0.w));
  *(ushort4*)(ybf + (size_t)row*DI + 256 + lane*4) = make_ushort4(f2bf(y1.x), f2bf(y1.y), f2bf(y1.z), f2bf(y1.w));
}

// ---------------- weight transpose+convert ----------------

// WtA[n][k] = bf16(in_proj[k][n]),  n<1152, k<256
__global__ __launch_bounds__(256) void tcvt_in(const float* __restrict__ W, unsigned short* __restrict__ Wt) {
  int idx = blockIdx.x*256 + threadIdx.x;   // 1152*256
  int n = idx >> 8, k = idx & 255;
  Wt[idx] = f2bf(W[(size_t)k*DP + n]);
}

// WtO[n][k] = bf16(out_proj[k][n]),  n<256, k<512
__global__ __launch_bounds__(256) void tcvt_out(const float* __restrict__ W, unsigned short* __restrict__ Wt) {
  int idx = blockIdx.x*256 + threadIdx.x;   // 256*512
  int n = idx >> 9, k = idx & 511;
  Wt[idx] = f2bf(W[(size_t)k*DM + n]);
}

// ---------------- MFMA GEMMs ----------------
// Layout: A_lds/B_lds 128 rows x 64 bf16 (128B rows), kchunk (16B) xor-swizzled by (row&7).
// mfma_f32_16x16x32_bf16 fragments: A[m=lane&15][k=(lane>>4)*8+j]; B likewise on its row; C/D col=lane&15,row=quad*4+reg.

__global__ __launch_bounds__(256) void gemm_in_mfma(const unsigned short* __restrict__ Abf,
                                                    const unsigned short* __restrict__ Wt,
                                                    const unsigned int* __restrict__ ordp,
                                                    float* __restrict__ gate, float* __restrict__ xbc) {
  __shared__ unsigned short Alds[128*64];
  __shared__ unsigned short Blds[128*64];
  int tid = threadIdx.x, lane = tid & 63, w = tid >> 6;
  int rb = blockIdx.y*128, cb = blockIdx.x*128;
  int wm = (w & 1)*64, wn = (w >> 1)*64;
  const unsigned short* pA[4]; const unsigned short* pB[4];
  unsigned short* dA[4]; unsigned short* dB[4];
  #pragma unroll
  for (int s = 0; s < 4; ++s) {
    int inst = w*4 + s;
    int r = inst*8 + (lane >> 3);
    int cA = (lane & 7) ^ (r & 7);
    pA[s] = Abf + (size_t)ordp[rb + r]*DM + cA*8;
    pB[s] = Wt + (size_t)(cb + r)*DM + cA*8;
    dA[s] = &Alds[inst*512];
    dB[s] = &Blds[inst*512];
  }
  f32x4 zero = {0.f, 0.f, 0.f, 0.f};
  f32x4 acc[4][4];
  #pragma unroll
  for (int i = 0; i < 4; ++i)
    #pragma unroll
    for (int j = 0; j < 4; ++j) acc[i][j] = zero;
  int t = lane & 15, q = lane >> 4;
  for (int k0 = 0; k0 < DM; k0 += 64) {
    #pragma unroll
    for (int s = 0; s < 4; ++s) GLL16(pA[s] + k0, dA[s]);
    #pragma unroll
    for (int s = 0; s < 4; ++s) GLL16(pB[s] + k0, dB[s]);
    __syncthreads();
    #pragma unroll
    for (int ks = 0; ks < 2; ++ks) {
      short8 af[4], bfr[4];
      int cc = ks*4 + q;
      #pragma unroll
      for (int i = 0; i < 4; ++i) {
        int rr = wm + 16*i + t;
        af[i] = *(const short8*)&Alds[rr*64 + ((cc ^ (rr & 7))*8)];
      }
      #pragma unroll
      for (int j = 0; j < 4; ++j) {
        int rr = wn + 16*j + t;
        bfr[j] = *(const short8*)&Blds[rr*64 + ((cc ^ (rr & 7))*8)];
      }
      #pragma unroll
      for (int i = 0; i < 4; ++i)
        #pragma unroll
        for (int j = 0; j < 4; ++j)
          acc[i][j] = __builtin_amdgcn_mfma_f32_16x16x32_bf16(af[i], bfr[j], acc[i][j], 0, 0, 0);
    }
    __syncthreads();
  }
  float* dst; int ld;
  if (cb < DI) { dst = gate + cb; ld = DI; }
  else         { dst = xbc + (cb - DI); ld = CD; }
  #pragma unroll
  for (int i = 0; i < 4; ++i) {
    int rowb = rb + wm + 16*i + q*4;
    #pragma unroll
    for (int j = 0; j < 4; ++j) {
      int col = wn + 16*j + t;
      #pragma unroll
      for (int r = 0; r < 4; ++r)
        dst[(size_t)(rowb + r)*ld + col] = acc[i][j][r];
    }
  }
}

__global__ __launch_bounds__(256) void gemm_out_mfma(const unsigned short* __restrict__ Abf,
                                                     const unsigned short* __restrict__ Wt,
                                                     const unsigned int* __restrict__ ordp,
                                                     float* __restrict__ out) {
  __shared__ unsigned short Alds[128*64];
  __shared__ unsigned short Blds[128*64];
  __shared__ unsigned int ordl[128];
  int tid = threadIdx.x, lane = tid & 63, w = tid >> 6;
  int rb = blockIdx.y*128, cb = blockIdx.x*128;
  int wm = (w & 1)*64, wn = (w >> 1)*64;
  if (tid < 128) ordl[tid] = ordp[rb + tid];
  const unsigned short* pA[4]; const unsigned short* pB[4];
  unsigned short* dA[4]; unsigned short* dB[4];
  #pragma unroll
  for (int s = 0; s < 4; ++s) {
    int inst = w*4 + s;
    int r = inst*8 + (lane >> 3);
    int cA = (lane & 7) ^ (r & 7);
    pA[s] = Abf + (size_t)(rb + r)*DI + cA*8;
    pB[s] = Wt + (size_t)(cb + r)*DI + cA*8;
    dA[s] = &Alds[inst*512];
    dB[s] = &Blds[inst*512];
  }
  f32x4 zero = {0.f, 0.f, 0.f, 0.f};
  f32x4 acc[4][4];
  #pragma unroll
  for (int i = 0; i < 4; ++i)
    #pragma unroll
    for (int j = 0; j < 4; ++j) acc[i][j] = zero;
  int t = lane & 15, q = lane >> 4;
  for (int k0 = 0; k0 < DI; k0 += 64) {
    #pragma unroll
    for (int s = 0; s < 4; ++s) GLL16(pA[s] + k0, dA[s]);
    #pragma unroll
    for (int s = 0; s < 4; ++s) GLL16(pB[s] + k0, dB[s]);
    __syncthreads();
    #pragma unroll
    for (int ks = 0; ks < 2; ++ks) {
      short8 af[4], bfr[4];
      int cc = ks*4 + q;
      #pragma unroll
      for (int i = 0; i < 4; ++i) {
        int rr = wm + 16*i + t;
        af[i] = *(const short8*)&Alds[rr*64 + ((cc ^ (rr & 7))*8)];
      }
      #pragma unroll
      for (int j = 0; j < 4; ++j) {
        int rr = wn + 16*j + t;
        bfr[j] = *(const short8*)&Blds[rr*64 + ((cc ^ (rr & 7))*8)];
      }
      #pragma unroll
      for (int i = 0; i < 4; ++i)
        #pragma unroll
        for (int j = 0; j < 4; ++j)
          acc[i][j] = __builtin_amdgcn_mfma_f32_16x16x32_bf16(af[i], bfr[j], acc[i][j], 0, 0, 0);
    }
    __syncthreads();
  }
  #pragma unroll
  for (int i = 0; i < 4; ++i) {
    #pragma unroll
    for (int r = 0; r < 4; ++r) {
      unsigned int tok = ordl[wm + 16*i + q*4 + r];
      float* op = out + (size_t)tok*DM + cb;
      #pragma unroll
      for (int j = 0; j < 4; ++j) {
        int col = wn + 16*j + t;
        op[col] += 0.5f*acc[i][j][r];
      }
    }
  }
}

// ---------------- dt path (fp32, fused softplus) ----------------
// one wave per sorted row: dt[row][h] = softplus( qn[ord[row]] . W[:,1152+h] + bias[h] )
__global__ __launch_bounds__(256) void dt_gemv(const float* __restrict__ qn, const float* __restrict__ W,
                                               const unsigned int* __restrict__ ordp,
                                               const float* __restrict__ dt_bias, float* __restrict__ dtb) {
  int row = blockIdx.x*4 + (threadIdx.x >> 6);
  int lane = threadIdx.x & 63;
  unsigned int src = ordp[row];
  const float4 q4 = *(const float4*)(qn + (size_t)src*DM + lane*4);
  float a[8] = {0,0,0,0,0,0,0,0};
  const float* wp = W + (size_t)(lane*4)*DP + (DI + CD);
  float qe[4] = {q4.x, q4.y, q4.z, q4.w};
  #pragma unroll
  for (int e = 0; e < 4; ++e) {
    float4 wa = *(const float4*)(wp + (size_t)e*DP);
    float4 wb = *(const float4*)(wp + (size_t)e*DP + 4);
    a[0] += qe[e]*wa.x; a[1] += qe[e]*wa.y; a[2] += qe[e]*wa.z; a[3] += qe[e]*wa.w;
    a[4] += qe[e]*wb.x; a[5] += qe[e]*wb.y; a[6] += qe[e]*wb.z; a[7] += qe[e]*wb.w;
  }
  #pragma unroll
  for (int h = 0; h < 8; ++h) a[h] = warp_sum(a[h]);
  float v = 0.0f;
  #pragma unroll
  for (int h = 0; h < 8; ++h) if (lane == h) v = a[h];
  if (lane < 8) {
    v += dt_bias[lane];
    float sp = (v > 0.0f) ? (v + log1pf(expf(-v))) : log1pf(expf(v));
    dtb[(size_t)row*NH + lane] = sp;
  }
}

// ---------------- conv ----------------

__global__ __launch_bounds__(256) void conv_kernel(const float* __restrict__ xbc, const float* __restrict__ cw,
                                                   const float* __restrict__ cbias, float* __restrict__ outc) {
  int idx = blockIdx.x*256 + threadIdx.x;
  if (idx >= L_TOK*CD) return;
  int c = idx % CD;
  int t = idx / CD;
  float s = cbias[c];
  #pragma unroll
  for (int kk = 0; kk < 4; ++kk) {
    int tt = t - 3 + kk;
    if (tt >= 0) s += cw[c*4+kk] * xbc[(size_t)tt*CD + c];
  }
  outc[idx] = siluf(s);
}

// ---------------- chunked scan ----------------

__global__ __launch_bounds__(256) void phaseA_kernel(const float* __restrict__ xc, const float* __restrict__ dtb,
                                                     const float* __restrict__ A_log,
                                                     float* __restrict__ S, float* __restrict__ P) {
  int c = blockIdx.x, h = blockIdx.y;
  int tid = threadIdx.x;
  __shared__ float xl[CHUNK][68];
  __shared__ float Bl[CHUNK][68];
  __shared__ float dts[CHUNK], lg[CHUNK], sfx[CHUNK], wgt[CHUNK];
  __shared__ float totals;
  int c0 = c*CHUNK;
  float Ah = -expf(A_log[h]);
  if (tid < CHUNK) {
    float dtv = dtb[(size_t)(c0+tid)*NH + h];
    dts[tid] = dtv;
    lg[tid] = dtv * Ah;
  }
  #pragma unroll
  for (int i = 0; i < 4; ++i) {
    int qq = tid + 256*i;
    int t = qq >> 4, cc = (qq & 15)*4;
    float4 v = *(const float4*)(xc + (size_t)(c0+t)*CD + DI + cc);
    *(float4*)&Bl[t][cc] = v;
  }
  __syncthreads();
  if (tid == 0) {
    float run = 0.0f;
    for (int t = CHUNK-1; t >= 0; --t) { sfx[t] = run; run += lg[t]; }
    totals = run;
  }
  __syncthreads();
  if (tid < CHUNK) wgt[tid] = dts[tid] * expf(sfx[tid]);
  if (tid == 0) P[h*NC + c] = expf(totals);
  __syncthreads();
  #pragma unroll
  for (int i = 0; i < 4; ++i) {
    int qq = tid + 256*i;
    int t = qq >> 4, cc = (qq & 15)*4;
    float4 v = *(const float4*)(xc + (size_t)(c0+t)*CD + h*HD + cc);
    float wv = wgt[t];
    v.x *= wv; v.y *= wv; v.z *= wv; v.w *= wv;
    *(float4*)&xl[t][cc] = v;
  }
  __syncthreads();
  int tx = tid & 15, ty = tid >> 4;
  float acc[4][4] = {};
  for (int t = 0; t < CHUNK; ++t) {
    float4 xv = *(const float4*)&xl[t][ty*4];
    float4 bv = *(const float4*)&Bl[t][tx*4];
    float xa[4] = {xv.x, xv.y, xv.z, xv.w};
    float ba[4] = {bv.x, bv.y, bv.z, bv.w};
    #pragma unroll
    for (int i = 0; i < 4; ++i)
      #pragma unroll
      for (int j = 0; j < 4; ++j)
        acc[i][j] += xa[i]*ba[j];
  }
  float* Sp = S + ((size_t)(h*NC + c))*4096;
  #pragma unroll
  for (int i = 0; i < 4; ++i) {
    float4 o = make_float4(acc[i][0], acc[i][1], acc[i][2], acc[i][3]);
    *(float4*)(Sp + (size_t)(ty*4+i)*64 + tx*4) = o;
  }
}

__global__ __launch_bounds__(256) void phaseB_kernel(float* __restrict__ S, const float* __restrict__ P) {
  int h = blockIdx.x >> 4;
  int e = (blockIdx.x & 15)*256 + threadIdx.x;
  size_t base = (size_t)h * NC * 4096 + e;
  const float* Ph = P + h*NC;
  float hs = 0.0f;
  float buf[4], nbuf[4];
  #pragma unroll
  for (int k = 0; k < 4; ++k) buf[k] = S[base + (size_t)k*4096];
  for (int c = 0; c < NC; c += 4) {
    if (c + 4 < NC) {
      #pragma unroll
      for (int k = 0; k < 4; ++k) nbuf[k] = S[base + (size_t)(c+4+k)*4096];
    }
    #pragma unroll
    for (int k = 0; k < 4; ++k) {
      S[base + (size_t)(c+k)*4096] = hs;
      hs = Ph[c+k]*hs + buf[k];
    }
    #pragma unroll
    for (int k = 0; k < 4; ++k) buf[k] = nbuf[k];
  }
}

__global__ __launch_bounds__(256) void phaseC_kernel(const float* __restrict__ xc, const float* __restrict__ dtb,
                                                     const float* __restrict__ A_log, const float* __restrict__ Dp,
                                                     const float* __restrict__ S, float* __restrict__ y) {
  int c = blockIdx.x, h = blockIdx.y, tid = threadIdx.x;
  __shared__ float Cl[CHUNK][68];
  __shared__ float Bl[CHUNK][68];
  __shared__ float xlT[HD][68];
  __shared__ float h0[HD][68];
  __shared__ float G[CHUNK][68];
  __shared__ float dts[CHUNK], lg[CHUNK], pl[CHUNK], pe[CHUNK];
  int c0 = c*CHUNK;
  float Ah = -expf(A_log[h]);
  float Dh = Dp[h];
  if (tid < CHUNK) {
    float dtv = dtb[(size_t)(c0+tid)*NH + h];
    dts[tid] = dtv;
    lg[tid] = dtv*Ah;
  }
  const float* Sp = S + ((size_t)(h*NC + c))*4096;
  #pragma unroll
  for (int i = 0; i < 4; ++i) {
    int qq = tid + 256*i;
    int t = qq >> 4, cc = (qq & 15)*4;
    float4 cv = *(const float4*)(xc + (size_t)(c0+t)*CD + DI + DS + cc);
    *(float4*)&Cl[t][cc] = cv;
    float4 bv = *(const float4*)(xc + (size_t)(c0+t)*CD + DI + cc);
    *(float4*)&Bl[t][cc] = bv;
    float4 xv = *(const float4*)(xc + (size_t)(c0+t)*CD + h*HD + cc);
    xlT[cc+0][t] = xv.x; xlT[cc+1][t] = xv.y; xlT[cc+2][t] = xv.z; xlT[cc+3][t] = xv.w;
    float4 hv = *(const float4*)(Sp + (size_t)t*64 + cc);
    *(float4*)&h0[t][cc] = hv;
  }
  __syncthreads();
  if (tid == 0) {
    float run = 0.0f;
    for (int t = 0; t < CHUNK; ++t) { run += lg[t]; pl[t] = run; }
  }
  __syncthreads();
  if (tid < CHUNK) pe[tid] = expf(pl[tid]);
  __syncthreads();
  int tx = tid & 15, ty = tid >> 4;
  {
    float acc[4][4] = {};
    for (int d = 0; d < DS; d += 4) {
      float4 cv[4], bv[4];
      #pragma unroll
      for (int i = 0; i < 4; ++i) cv[i] = *(const float4*)&Cl[ty + 16*i][d];
      #pragma unroll
      for (int j = 0; j < 4; ++j) bv[j] = *(const float4*)&Bl[tx + 16*j][d];
      #pragma unroll
      for (int i = 0; i < 4; ++i)
        #pragma unroll
        for (int j = 0; j < 4; ++j)
          acc[i][j] += dot4f(cv[i], bv[j]);
    }
    #pragma unroll
    for (int i = 0; i < 4; ++i) {
      int t = ty + 16*i;
      #pragma unroll
      for (int j = 0; j < 4; ++j) {
        int s = tx + 16*j;
        float v = 0.0f;
        if (s <= t) v = acc[i][j] * dts[s] * expf(pl[t] - pl[s]);
        G[t][s] = v;
      }
    }
  }
  __syncthreads();
  {
    float acc[4][4] = {};
    for (int d = 0; d < DS; d += 4) {
      float4 cv[4], hv[4];
      #pragma unroll
      for (int i = 0; i < 4; ++i) cv[i] = *(const float4*)&Cl[ty + 16*i][d];
      #pragma unroll
      for (int j = 0; j < 4; ++j) hv[j] = *(const float4*)&h0[tx + 16*j][d];
      #pragma unroll
      for (int i = 0; i < 4; ++i)
        #pragma unroll
        for (int j = 0; j < 4; ++j)
          acc[i][j] += dot4f(cv[i], hv[j]);
    }
    #pragma unroll
    for (int i = 0; i < 4; ++i) {
      float sc = pe[ty + 16*i];
      #pragma unroll
      for (int j = 0; j < 4; ++j) acc[i][j] *= sc;
    }
    for (int s = 0; s < CHUNK; s += 4) {
      float4 gv[4], xv[4];
      #pragma unroll
      for (int i = 0; i < 4; ++i) gv[i] = *(const float4*)&G[ty + 16*i][s];
      #pragma unroll
      for (int j = 0; j < 4; ++j) xv[j] = *(const float4*)&xlT[tx + 16*j][s];
      #pragma unroll
      for (int i = 0; i < 4; ++i)
        #pragma unroll
        for (int j = 0; j < 4; ++j)
          acc[i][j] += dot4f(gv[i], xv[j]);
    }
    #pragma unroll
    for (int i = 0; i < 4; ++i) {
      int t = ty + 16*i;
      #pragma unroll
      for (int j = 0; j < 4; ++j) {
        int p = tx + 16*j;
        float v = acc[i][j] + Dh * xlT[p][t];
        y[(size_t)(c0+t)*DI + h*HD + p] = v;
      }
    }
  }
}

__global__ void fill_debug(float* out, float v) {
  int i = blockIdx.x*256 + threadIdx.x;
  if (i < L_TOK*DM) out[i] = v;
}

// ---------------- host ----------------

extern "C" void kernel_launch(void* const* d_in, const int* in_sizes, int n_in,
                              void* d_out, int out_size, void* d_ws, size_t ws_size,
                              hipStream_t stream) {
  const float* query = (const float*)d_in[0];
  const float* qpos  = (const float*)d_in[1];
  const float* pre_w = (const float*)d_in[2];
  const float* pre_b = (const float*)d_in[3];
  const float* fin_w = (const float*)d_in[4];
  const float* fin_b = (const float*)d_in[5];
  float* out = (float*)d_out;

  char* ws = (char*)d_ws;
  size_t off = 0;
  auto alloc = [&](size_t bytes) -> void* {
    void* p = ws + off;
    off += (bytes + 255) & ~(size_t)255;
    return p;
  };
  unsigned long long* keys = (unsigned long long*)alloc((size_t)2*L_TOK*8);
  unsigned int* ord = (unsigned int*)alloc((size_t)2*L_TOK*4);
  unsigned int* rpart = (unsigned int*)alloc((size_t)4*2*L_TOK*4);
  float* pmm  = (float*)alloc(256);
  float* qn   = (float*)alloc((size_t)L_TOK*DM*4);
  unsigned short* qnbf = (unsigned short*)alloc((size_t)L_TOK*DM*2);
  float* gate = (float*)alloc((size_t)L_TOK*DI*4);
  float* xbc  = (float*)alloc((size_t)L_TOK*CD*4);   // reused as y after conv
  float* convo= (float*)alloc((size_t)L_TOK*CD*4);
  float* dtb  = (float*)alloc((size_t)L_TOK*NH*4);
  float* Sbuf = (float*)alloc((size_t)NH*NC*4096*4);
  float* Pbuf = (float*)alloc((size_t)NH*NC*4);
  unsigned short* ybf = (unsigned short*)alloc((size_t)L_TOK*DI*2);
  unsigned short* WtA = (unsigned short*)alloc((size_t)1152*DM*2);
  unsigned short* WtO = (unsigned short*)alloc((size_t)DM*DI*2);
  if (off > ws_size) {
    fill_debug<<<(L_TOK*DM + 255)/256, 256, 0, stream>>>(out, (float)(ws_size >> 20));
    return;
  }

  minmax_kernel<<<1, 256, 0, stream>>>(qpos, pmm);
  hilbert_kernel<<<L_TOK/256, 256, 0, stream>>>(qpos, pmm, keys);
  rank_partial<<<dim3(L_TOK/256, 2, 4), 256, 0, stream>>>(keys, rpart);
  rank_scatter<<<(2*L_TOK)/256, 256, 0, stream>>>(keys, rpart, ord);
  hipMemcpyAsync(out, query, (size_t)L_TOK*DM*4, hipMemcpyDeviceToDevice, stream);

  for (int l = 0; l < 2; ++l) {
    int base = 6 + 8*l;
    const float* in_proj  = (const float*)d_in[base+0];
    const float* conv_w   = (const float*)d_in[base+1];
    const float* conv_b   = (const float*)d_in[base+2];
    const float* dt_bias  = (const float*)d_in[base+3];
    const float* A_log    = (const float*)d_in[base+4];
    const float* Dp       = (const float*)d_in[base+5];
    const float* norm_w   = (const float*)d_in[base+6];
    const float* out_proj = (const float*)d_in[base+7];

    ln_kernel<<<L_TOK/4, 256, 0, stream>>>(out, qn, qnbf, pre_w, pre_b);
    tcvt_in<<<(1152*DM)/256, 256, 0, stream>>>(in_proj, WtA);
    tcvt_out<<<(DM*DI)/256, 256, 0, stream>>>(out_proj, WtO);
    for (int dir = 0; dir < 2; ++dir) {
      const unsigned int* o = ord + (size_t)dir*L_TOK;
      gemm_in_mfma<<<dim3(9, L_TOK/128), 256, 0, stream>>>(qnbf, WtA, o, gate, xbc);
      dt_gemv<<<L_TOK/4, 256, 0, stream>>>(qn, in_proj, o, dt_bias, dtb);
      conv_kernel<<<(L_TOK*CD)/256, 256, 0, stream>>>(xbc, conv_w, conv_b, convo);
      phaseA_kernel<<<dim3(NC, NH), 256, 0, stream>>>(convo, dtb, A_log, Sbuf, Pbuf);
      phaseB_kernel<<<128, 256, 0, stream>>>(Sbuf, Pbuf);
      phaseC_kernel<<<dim3(NC, NH), 256, 0, stream>>>(convo, dtb, A_log, Dp, Sbuf, xbc);
      gating_kernel<<<L_TOK/4, 256, 0, stream>>>(xbc, gate, norm_w, ybf);
      gemm_out_mfma<<<dim3(2, L_TOK/128), 256, 0, stream>>>(ybf, WtO, o, out);
    }
    ln_kernel<<<L_TOK/4, 256, 0, stream>>>(out, out, (unsigned short*)nullptr, fin_w, fin_b);
  }
}

// Round 4
// 986.770 us; speedup vs baseline: 2.6048x; 1.3209x over previous
//
#include <hip/hip_runtime.h>
#include <stdint.h>

#define L_TOK 16384
#define DM 256
#define DI 512
#define DS 64
#define NH 8
#define HD 64
#define CD 640
#define DP 1160
#define CHUNK 64
#define NC 256
#define EPSF 1e-5f

typedef __attribute__((ext_vector_type(8))) short short8;
typedef __attribute__((ext_vector_type(4))) float f32x4;

#define GLL16(gp, lp) __builtin_amdgcn_global_load_lds((const __attribute__((address_space(1))) void*)(gp), (__attribute__((address_space(3))) void*)(lp), 16, 0, 0)

__device__ __forceinline__ float warp_sum(float v) {
  v += __shfl_xor(v, 1, 64);
  v += __shfl_xor(v, 2, 64);
  v += __shfl_xor(v, 4, 64);
  v += __shfl_xor(v, 8, 64);
  v += __shfl_xor(v, 16, 64);
  v += __shfl_xor(v, 32, 64);
  return v;
}

__device__ __forceinline__ float siluf(float x) { return x / (1.0f + expf(-x)); }

// round-to-nearest-even f32 -> bf16
__device__ __forceinline__ unsigned short f2bf(float f) {
  unsigned int u = __float_as_uint(f);
  unsigned int r = (u + 0x7FFFu + ((u >> 16) & 1u)) >> 16;
  return (unsigned short)r;
}
__device__ __forceinline__ float bf2f(unsigned short u) {
  return __uint_as_float(((unsigned int)u) << 16);
}
__device__ __forceinline__ short8 cvt8(const float4 a, const float4 b) {
  short8 r;
  r[0]=(short)f2bf(a.x); r[1]=(short)f2bf(a.y); r[2]=(short)f2bf(a.z); r[3]=(short)f2bf(a.w);
  r[4]=(short)f2bf(b.x); r[5]=(short)f2bf(b.y); r[6]=(short)f2bf(b.z); r[7]=(short)f2bf(b.w);
  return r;
}

// ---------------- serialization ----------------

__global__ __launch_bounds__(256) void minmax_kernel(const float* __restrict__ pos, float* __restrict__ pmm) {
  __shared__ float sm[6][256];
  int tid = threadIdx.x;
  float mn0=1e30f, mn1=1e30f, mn2=1e30f, mx0=-1e30f, mx1=-1e30f, mx2=-1e30f;
  for (int t = tid; t < L_TOK; t += 256) {
    float a = pos[t*3+0], b = pos[t*3+1], c = pos[t*3+2];
    mn0=fminf(mn0,a); mx0=fmaxf(mx0,a);
    mn1=fminf(mn1,b); mx1=fmaxf(mx1,b);
    mn2=fminf(mn2,c); mx2=fmaxf(mx2,c);
  }
  sm[0][tid]=mn0; sm[1][tid]=mn1; sm[2][tid]=mn2;
  sm[3][tid]=mx0; sm[4][tid]=mx1; sm[5][tid]=mx2;
  __syncthreads();
  for (int s = 128; s > 0; s >>= 1) {
    if (tid < s) {
      #pragma unroll
      for (int d = 0; d < 3; ++d) {
        sm[d][tid]   = fminf(sm[d][tid],   sm[d][tid+s]);
        sm[3+d][tid] = fmaxf(sm[3+d][tid], sm[3+d][tid+s]);
      }
    }
    __syncthreads();
  }
  if (tid < 6) pmm[tid] = sm[tid][0];
}

__device__ unsigned int hilbert3(unsigned int a, unsigned int b, unsigned int c) {
  unsigned int x0 = a, x1 = b, x2 = c;
  for (unsigned int Q = 512u; Q > 1u; Q >>= 1) {
    unsigned int P = Q - 1u;
    { if (x0 & Q) x0 ^= P; }
    {
      unsigned int t = (x0 ^ x1) & P;
      if (x1 & Q) { x0 ^= P; }
      else { x0 ^= t; x1 ^= t; }
    }
    {
      unsigned int t = (x0 ^ x2) & P;
      if (x2 & Q) { x0 ^= P; }
      else { x0 ^= t; x2 ^= t; }
    }
  }
  x1 ^= x0; x2 ^= x1;
  unsigned int tt = 0;
  for (unsigned int Q = 512u; Q > 1u; Q >>= 1)
    if (x2 & Q) tt ^= (Q - 1u);
  x0 ^= tt; x1 ^= tt; x2 ^= tt;
  unsigned int code = 0;
  #pragma unroll
  for (int bb = 9; bb >= 0; --bb) {
    code = (code << 1) | ((x0 >> bb) & 1u);
    code = (code << 1) | ((x1 >> bb) & 1u);
    code = (code << 1) | ((x2 >> bb) & 1u);
  }
  return code;
}

__global__ __launch_bounds__(256) void hilbert_kernel(const float* __restrict__ pos, const float* __restrict__ pmm,
                                                      unsigned long long* __restrict__ keys) {
  int t = blockIdx.x*256 + threadIdx.x;
  if (t >= L_TOK) return;
  unsigned int g[3];
  #pragma unroll
  for (int d = 0; d < 3; ++d) {
    float v = (pos[t*3+d] - pmm[d]) / (pmm[3+d] - pmm[d] + 1e-6f) * 1023.0f;
    v = fminf(fmaxf(v, 0.0f), 1023.0f);
    g[d] = (unsigned int)(int)v;
  }
  unsigned int ca = hilbert3(g[0], g[1], g[2]);
  unsigned int cb = hilbert3(g[1], g[0], g[2]);
  keys[t]         = ((unsigned long long)ca << 14) | (unsigned long long)t;
  keys[L_TOK + t] = ((unsigned long long)cb << 14) | (unsigned long long)t;
}

__global__ __launch_bounds__(256) void rank_partial(const unsigned long long* __restrict__ keys,
                                                    unsigned int* __restrict__ partial) {
  __shared__ unsigned long long tile[4096];
  int arr = blockIdx.y, ks = blockIdx.z;
  const unsigned long long* k = keys + (size_t)arr * L_TOK;
  int qi = blockIdx.x*256 + threadIdx.x;
  unsigned long long my = k[qi];
  const unsigned long long* src = k + ks*4096;
  #pragma unroll
  for (int t = 0; t < 16; ++t) tile[threadIdx.x + 256*t] = src[threadIdx.x + 256*t];
  __syncthreads();
  int r = 0;
  const ulonglong2* t2 = (const ulonglong2*)tile;
  #pragma unroll 8
  for (int j = 0; j < 2048; ++j) {
    ulonglong2 v = t2[j];
    r += (v.x < my) ? 1 : 0;
    r += (v.y < my) ? 1 : 0;
  }
  partial[(size_t)(ks*2 + arr)*L_TOK + qi] = (unsigned int)r;
}

__global__ __launch_bounds__(256) void rank_scatter(const unsigned long long* __restrict__ keys,
                                                    const unsigned int* __restrict__ partial,
                                                    unsigned int* __restrict__ ord) {
  int i = blockIdx.x*256 + threadIdx.x;
  int arr = i >> 14;
  int qi = i & (L_TOK - 1);
  unsigned int r = 0;
  #pragma unroll
  for (int ks = 0; ks < 4; ++ks) r += partial[(size_t)(ks*2 + arr)*L_TOK + qi];
  ord[(size_t)arr*L_TOK + r] = (unsigned int)(keys[i] & 0x3FFFu);
}

// ---------------- layernorm / gating ----------------

__global__ __launch_bounds__(256) void ln_kernel(const float* __restrict__ in, float* __restrict__ out,
                                                 unsigned short* __restrict__ outbf,
                                                 const float* __restrict__ w, const float* __restrict__ b) {
  int row = blockIdx.x*4 + (threadIdx.x >> 6);
  int lane = threadIdx.x & 63;
  const float4 v = *(const float4*)(in + (size_t)row*DM + lane*4);
  float s = v.x + v.y + v.z + v.w;
  float mean = warp_sum(s) * (1.0f/DM);
  float4 xc = make_float4(v.x-mean, v.y-mean, v.z-mean, v.w-mean);
  float ss = xc.x*xc.x + xc.y*xc.y + xc.z*xc.z + xc.w*xc.w;
  ss = warp_sum(ss) * (1.0f/DM);
  float inv = rsqrtf(ss + EPSF);
  const float4 w4 = *(const float4*)(w + lane*4);
  const float4 b4 = *(const float4*)(b + lane*4);
  float4 o;
  o.x = xc.x*inv*w4.x + b4.x;
  o.y = xc.y*inv*w4.y + b4.y;
  o.z = xc.z*inv*w4.z + b4.z;
  o.w = xc.w*inv*w4.w + b4.w;
  *(float4*)(out + (size_t)row*DM + lane*4) = o;
  if (outbf) {
    ushort4 ob = make_ushort4(f2bf(o.x), f2bf(o.y), f2bf(o.z), f2bf(o.w));
    *(ushort4*)(outbf + (size_t)row*DM + lane*4) = ob;
  }
}

__global__ __launch_bounds__(256) void gating_kernel(const float* __restrict__ y, const float* __restrict__ gate,
                                                     const float* __restrict__ nw, unsigned short* __restrict__ ybf) {
  int row = blockIdx.x*4 + (threadIdx.x >> 6);
  int lane = threadIdx.x & 63;
  const float* yr = y + (size_t)row*DI;
  const float* gr = gate + (size_t)row*DI;
  float4 y0 = *(const float4*)(yr + lane*4);
  float4 y1 = *(const float4*)(yr + 256 + lane*4);
  const float4 g0 = *(const float4*)(gr + lane*4);
  const float4 g1 = *(const float4*)(gr + 256 + lane*4);
  y0.x *= siluf(g0.x); y0.y *= siluf(g0.y); y0.z *= siluf(g0.z); y0.w *= siluf(g0.w);
  y1.x *= siluf(g1.x); y1.y *= siluf(g1.y); y1.z *= siluf(g1.z); y1.w *= siluf(g1.w);
  float ss = y0.x*y0.x + y0.y*y0.y + y0.z*y0.z + y0.w*y0.w
           + y1.x*y1.x + y1.y*y1.y + y1.z*y1.z + y1.w*y1.w;
  ss = warp_sum(ss) * (1.0f/DI);
  float inv = rsqrtf(ss + EPSF);
  const float4 w0 = *(const float4*)(nw + lane*4);
  const float4 w1 = *(const float4*)(nw + 256 + lane*4);
  y0.x *= inv*w0.x; y0.y *= inv*w0.y; y0.z *= inv*w0.z; y0.w *= inv*w0.w;
  y1.x *= inv*w1.x; y1.y *= inv*w1.y; y1.z *= inv*w1.z; y1.w *= inv*w1.w;
  *(ushort4*)(ybf + (size_t)row*DI + lane*4)       = make_ushort4(f2bf(y0.x), f2bf(y0.y), f2bf(y0.z), f2bf(y0.w));
  *(ushort4*)(ybf + (size_t)row*DI + 256 + lane*4) = make_ushort4(f2bf(y1.x), f2bf(y1.y), f2bf(y1.z), f2bf(y1.w));
}

// ---------------- weight transpose+convert ----------------

__global__ __launch_bounds__(256) void tcvt_in(const float* __restrict__ W, unsigned short* __restrict__ Wt) {
  int idx = blockIdx.x*256 + threadIdx.x;
  int n = idx >> 8, k = idx & 255;
  Wt[idx] = f2bf(W[(size_t)k*DP + n]);
}

__global__ __launch_bounds__(256) void tcvt_out(const float* __restrict__ W, unsigned short* __restrict__ Wt) {
  int idx = blockIdx.x*256 + threadIdx.x;
  int n = idx >> 9, k = idx & 511;
  Wt[idx] = f2bf(W[(size_t)k*DM + n]);
}

// ---------------- MFMA GEMMs ----------------

__global__ __launch_bounds__(256) void gemm_in_mfma(const unsigned short* __restrict__ Abf,
                                                    const unsigned short* __restrict__ Wt,
                                                    const unsigned int* __restrict__ ordp,
                                                    float* __restrict__ gate, float* __restrict__ xbc) {
  __shared__ unsigned short Alds[128*64];
  __shared__ unsigned short Blds[128*64];
  int tid = threadIdx.x, lane = tid & 63, w = tid >> 6;
  int rb = blockIdx.y*128, cb = blockIdx.x*128;
  int wm = (w & 1)*64, wn = (w >> 1)*64;
  const unsigned short* pA[4]; const unsigned short* pB[4];
  unsigned short* dA[4]; unsigned short* dB[4];
  #pragma unroll
  for (int s = 0; s < 4; ++s) {
    int inst = w*4 + s;
    int r = inst*8 + (lane >> 3);
    int cA = (lane & 7) ^ (r & 7);
    pA[s] = Abf + (size_t)ordp[rb + r]*DM + cA*8;
    pB[s] = Wt + (size_t)(cb + r)*DM + cA*8;
    dA[s] = &Alds[inst*512];
    dB[s] = &Blds[inst*512];
  }
  f32x4 zero = {0.f, 0.f, 0.f, 0.f};
  f32x4 acc[4][4];
  #pragma unroll
  for (int i = 0; i < 4; ++i)
    #pragma unroll
    for (int j = 0; j < 4; ++j) acc[i][j] = zero;
  int t = lane & 15, q = lane >> 4;
  for (int k0 = 0; k0 < DM; k0 += 64) {
    #pragma unroll
    for (int s = 0; s < 4; ++s) GLL16(pA[s] + k0, dA[s]);
    #pragma unroll
    for (int s = 0; s < 4; ++s) GLL16(pB[s] + k0, dB[s]);
    __syncthreads();
    #pragma unroll
    for (int ks = 0; ks < 2; ++ks) {
      short8 af[4], bfr[4];
      int cc = ks*4 + q;
      #pragma unroll
      for (int i = 0; i < 4; ++i) {
        int rr = wm + 16*i + t;
        af[i] = *(const short8*)&Alds[rr*64 + ((cc ^ (rr & 7))*8)];
      }
      #pragma unroll
      for (int j = 0; j < 4; ++j) {
        int rr = wn + 16*j + t;
        bfr[j] = *(const short8*)&Blds[rr*64 + ((cc ^ (rr & 7))*8)];
      }
      #pragma unroll
      for (int i = 0; i < 4; ++i)
        #pragma unroll
        for (int j = 0; j < 4; ++j)
          acc[i][j] = __builtin_amdgcn_mfma_f32_16x16x32_bf16(af[i], bfr[j], acc[i][j], 0, 0, 0);
    }
    __syncthreads();
  }
  float* dst; int ld;
  if (cb < DI) { dst = gate + cb; ld = DI; }
  else         { dst = xbc + (cb - DI); ld = CD; }
  #pragma unroll
  for (int i = 0; i < 4; ++i) {
    int rowb = rb + wm + 16*i + q*4;
    #pragma unroll
    for (int j = 0; j < 4; ++j) {
      int col = wn + 16*j + t;
      #pragma unroll
      for (int r = 0; r < 4; ++r)
        dst[(size_t)(rowb + r)*ld + col] = acc[i][j][r];
    }
  }
}

__global__ __launch_bounds__(256) void gemm_out_mfma(const unsigned short* __restrict__ Abf,
                                                     const unsigned short* __restrict__ Wt,
                                                     const unsigned int* __restrict__ ordp,
                                                     float* __restrict__ out) {
  __shared__ unsigned short Alds[128*64];
  __shared__ unsigned short Blds[128*64];
  __shared__ unsigned int ordl[128];
  int tid = threadIdx.x, lane = tid & 63, w = tid >> 6;
  int rb = blockIdx.y*128, cb = blockIdx.x*128;
  int wm = (w & 1)*64, wn = (w >> 1)*64;
  if (tid < 128) ordl[tid] = ordp[rb + tid];
  const unsigned short* pA[4]; const unsigned short* pB[4];
  unsigned short* dA[4]; unsigned short* dB[4];
  #pragma unroll
  for (int s = 0; s < 4; ++s) {
    int inst = w*4 + s;
    int r = inst*8 + (lane >> 3);
    int cA = (lane & 7) ^ (r & 7);
    pA[s] = Abf + (size_t)(rb + r)*DI + cA*8;
    pB[s] = Wt + (size_t)(cb + r)*DI + cA*8;
    dA[s] = &Alds[inst*512];
    dB[s] = &Blds[inst*512];
  }
  f32x4 zero = {0.f, 0.f, 0.f, 0.f};
  f32x4 acc[4][4];
  #pragma unroll
  for (int i = 0; i < 4; ++i)
    #pragma unroll
    for (int j = 0; j < 4; ++j) acc[i][j] = zero;
  int t = lane & 15, q = lane >> 4;
  for (int k0 = 0; k0 < DI; k0 += 64) {
    #pragma unroll
    for (int s = 0; s < 4; ++s) GLL16(pA[s] + k0, dA[s]);
    #pragma unroll
    for (int s = 0; s < 4; ++s) GLL16(pB[s] + k0, dB[s]);
    __syncthreads();
    #pragma unroll
    for (int ks = 0; ks < 2; ++ks) {
      short8 af[4], bfr[4];
      int cc = ks*4 + q;
      #pragma unroll
      for (int i = 0; i < 4; ++i) {
        int rr = wm + 16*i + t;
        af[i] = *(const short8*)&Alds[rr*64 + ((cc ^ (rr & 7))*8)];
      }
      #pragma unroll
      for (int j = 0; j < 4; ++j) {
        int rr = wn + 16*j + t;
        bfr[j] = *(const short8*)&Blds[rr*64 + ((cc ^ (rr & 7))*8)];
      }
      #pragma unroll
      for (int i = 0; i < 4; ++i)
        #pragma unroll
        for (int j = 0; j < 4; ++j)
          acc[i][j] = __builtin_amdgcn_mfma_f32_16x16x32_bf16(af[i], bfr[j], acc[i][j], 0, 0, 0);
    }
    __syncthreads();
  }
  #pragma unroll
  for (int i = 0; i < 4; ++i) {
    #pragma unroll
    for (int r = 0; r < 4; ++r) {
      unsigned int tok = ordl[wm + 16*i + q*4 + r];
      float* op = out + (size_t)tok*DM + cb;
      #pragma unroll
      for (int j = 0; j < 4; ++j) {
        int col = wn + 16*j + t;
        op[col] += 0.5f*acc[i][j][r];
      }
    }
  }
}

// ---------------- dt path (fp32, fused softplus) ----------------
__global__ __launch_bounds__(256) void dt_gemv(const float* __restrict__ qn, const float* __restrict__ W,
                                               const unsigned int* __restrict__ ordp,
                                               const float* __restrict__ dt_bias, float* __restrict__ dtb) {
  int row = blockIdx.x*4 + (threadIdx.x >> 6);
  int lane = threadIdx.x & 63;
  unsigned int src = ordp[row];
  const float4 q4 = *(const float4*)(qn + (size_t)src*DM + lane*4);
  float a[8] = {0,0,0,0,0,0,0,0};
  const float* wp = W + (size_t)(lane*4)*DP + (DI + CD);
  float qe[4] = {q4.x, q4.y, q4.z, q4.w};
  #pragma unroll
  for (int e = 0; e < 4; ++e) {
    float4 wa = *(const float4*)(wp + (size_t)e*DP);
    float4 wb = *(const float4*)(wp + (size_t)e*DP + 4);
    a[0] += qe[e]*wa.x; a[1] += qe[e]*wa.y; a[2] += qe[e]*wa.z; a[3] += qe[e]*wa.w;
    a[4] += qe[e]*wb.x; a[5] += qe[e]*wb.y; a[6] += qe[e]*wb.z; a[7] += qe[e]*wb.w;
  }
  #pragma unroll
  for (int h = 0; h < 8; ++h) a[h] = warp_sum(a[h]);
  float v = 0.0f;
  #pragma unroll
  for (int h = 0; h < 8; ++h) if (lane == h) v = a[h];
  if (lane < 8) {
    v += dt_bias[lane];
    float sp = (v > 0.0f) ? (v + log1pf(expf(-v))) : log1pf(expf(v));
    dtb[(size_t)row*NH + lane] = sp;
  }
}

// ---------------- conv (bf16 out) ----------------

__global__ __launch_bounds__(256) void conv_kernel(const float* __restrict__ xbc, const float* __restrict__ cw,
                                                   const float* __restrict__ cbias, unsigned short* __restrict__ outc) {
  int idx = blockIdx.x*256 + threadIdx.x;
  if (idx >= L_TOK*CD) return;
  int c = idx % CD;
  int t = idx / CD;
  float s = cbias[c];
  #pragma unroll
  for (int kk = 0; kk < 4; ++kk) {
    int tt = t - 3 + kk;
    if (tt >= 0) s += cw[c*4+kk] * xbc[(size_t)tt*CD + c];
  }
  outc[idx] = f2bf(siluf(s));
}

// ---------------- chunked scan (MFMA) ----------------
// LDS layout convention: row-major 64 rows x 64 bf16, 8-el chunk index xor-swizzled by (row&7).
// A-frag: row m=base+(lane&15), chunk (ks*4+quad)^(row&7).  B-frag: same with row n.

// S_c[p][s] = sum_t wgt[t]*x[t][p]*B[t][s];  wgt[t]=dt_t*exp(sfx[t]);  P_c = exp(total)
__global__ __launch_bounds__(256) void phaseA_mfma(const unsigned short* __restrict__ xc,
                                                   const float* __restrict__ dtb, const float* __restrict__ A_log,
                                                   float* __restrict__ S, float* __restrict__ P) {
  int c = blockIdx.x, h = blockIdx.y, tid = threadIdx.x;
  int lane = tid & 63, w = tid >> 6;
  __shared__ unsigned short xT[64*64];   // [p][t-sw]  (weighted)
  __shared__ unsigned short Bt[64*64];   // [s][t-sw]
  __shared__ float dts[64], lg[64], sfx[64], wgt[64];
  __shared__ float totals;
  int c0 = c*CHUNK;
  float Ah = -expf(A_log[h]);
  if (tid < 64) {
    float dtv = dtb[(size_t)(c0+tid)*NH + h];
    dts[tid] = dtv; lg[tid] = dtv*Ah;
  }
  // stage B transposed: read 8 consecutive s of row t -> rows s, col t
  #pragma unroll
  for (int i = 0; i < 2; ++i) {
    int q = tid + 256*i;
    int t = q >> 3, s0 = (q & 7)*8;
    short8 v = *(const short8*)(xc + (size_t)(c0+t)*CD + DI + s0);
    int tc = t >> 3, ti = t & 7;
    #pragma unroll
    for (int e = 0; e < 8; ++e) {
      int s = s0 + e;
      Bt[s*64 + ((tc ^ (s & 7))*8 + ti)] = (unsigned short)v[e];
    }
  }
  __syncthreads();
  if (tid == 0) {
    float run = 0.f;
    for (int t = 63; t >= 0; --t) { sfx[t] = run; run += lg[t]; }
    totals = run;
  }
  __syncthreads();
  if (tid < 64) wgt[tid] = dts[tid]*expf(sfx[tid]);
  if (tid == 0) P[h*NC + c] = expf(totals);
  __syncthreads();
  // stage x transposed with weight
  #pragma unroll
  for (int i = 0; i < 2; ++i) {
    int q = tid + 256*i;
    int t = q >> 3, p0 = (q & 7)*8;
    short8 v = *(const short8*)(xc + (size_t)(c0+t)*CD + h*HD + p0);
    float wv = wgt[t];
    int tc = t >> 3, ti = t & 7;
    #pragma unroll
    for (int e = 0; e < 8; ++e) {
      int p = p0 + e;
      xT[p*64 + ((tc ^ (p & 7))*8 + ti)] = f2bf(bf2f((unsigned short)v[e]) * wv);
    }
  }
  __syncthreads();
  int t16 = lane & 15, q4 = lane >> 4;
  f32x4 zero = {0.f,0.f,0.f,0.f};
  f32x4 acc[4];
  #pragma unroll
  for (int j = 0; j < 4; ++j) acc[j] = zero;
  #pragma unroll
  for (int ks = 0; ks < 2; ++ks) {
    int rowA = 16*w + t16;
    short8 a = *(const short8*)&xT[rowA*64 + (((ks*4 + q4) ^ (rowA & 7))*8)];
    #pragma unroll
    for (int j = 0; j < 4; ++j) {
      int rowB = 16*j + t16;
      short8 b = *(const short8*)&Bt[rowB*64 + (((ks*4 + q4) ^ (rowB & 7))*8)];
      acc[j] = __builtin_amdgcn_mfma_f32_16x16x32_bf16(a, b, acc[j], 0, 0, 0);
    }
  }
  float* Sp = S + ((size_t)(h*NC + c))*4096;
  #pragma unroll
  for (int j = 0; j < 4; ++j)
    #pragma unroll
    for (int r = 0; r < 4; ++r)
      Sp[(size_t)(16*w + q4*4 + r)*64 + 16*j + t16] = acc[j][r];
}

__global__ __launch_bounds__(256) void phaseB_kernel(float* __restrict__ S, const float* __restrict__ P) {
  int h = blockIdx.x >> 4;
  int e = (blockIdx.x & 15)*256 + threadIdx.x;
  size_t base = (size_t)h * NC * 4096 + e;
  const float* Ph = P + h*NC;
  float hs = 0.0f;
  float buf[4], nbuf[4];
  #pragma unroll
  for (int k = 0; k < 4; ++k) buf[k] = S[base + (size_t)k*4096];
  for (int c = 0; c < NC; c += 4) {
    if (c + 4 < NC) {
      #pragma unroll
      for (int k = 0; k < 4; ++k) nbuf[k] = S[base + (size_t)(c+4+k)*4096];
    }
    #pragma unroll
    for (int k = 0; k < 4; ++k) {
      S[base + (size_t)(c+k)*4096] = hs;
      hs = Ph[c+k]*hs + buf[k];
    }
    #pragma unroll
    for (int k = 0; k < 4; ++k) buf[k] = nbuf[k];
  }
}

// Y[t][p] = pe[t]*(C_t.h0[p]) + sum_s G[t][s]*x[s][p],  G[t][s]=dts[s]*exp(pl[t]-pl[s])*(C_t.B_s) [s<=t], G[t][t]+=D_h
__global__ __launch_bounds__(256) void phaseC_mfma(const unsigned short* __restrict__ xc,
                                                   const float* __restrict__ dtb, const float* __restrict__ A_log,
                                                   const float* __restrict__ Dp,
                                                   const float* __restrict__ S, float* __restrict__ y) {
  int c = blockIdx.x, h = blockIdx.y, tid = threadIdx.x;
  int lane = tid & 63, w = tid >> 6;
  __shared__ unsigned short Cl[64*64];   // [t][d-sw]
  __shared__ unsigned short Bl[64*64];   // [s][d-sw]
  __shared__ unsigned short h0l[64*64];  // [p][d-sw]
  __shared__ unsigned short xT[64*64];   // [p][s-sw]
  __shared__ unsigned short Gl[64*64];   // [t][s-sw]
  __shared__ float dts[64], lg[64], pl[64], pe[64];
  int c0 = c*CHUNK;
  float Ah = -expf(A_log[h]);
  float Dh = Dp[h];
  if (tid < 64) {
    float dtv = dtb[(size_t)(c0+tid)*NH + h];
    dts[tid] = dtv; lg[tid] = dtv*Ah;
  }
  const float* Sp = S + ((size_t)(h*NC + c))*4096;
  #pragma unroll
  for (int i = 0; i < 2; ++i) {
    int q = tid + 256*i;
    int t = q >> 3, d0 = (q & 7)*8;
    int swoff = t*64 + (((q & 7) ^ (t & 7))*8);
    *(short8*)&Cl[swoff] = *(const short8*)(xc + (size_t)(c0+t)*CD + DI + DS + d0);
    *(short8*)&Bl[swoff] = *(const short8*)(xc + (size_t)(c0+t)*CD + DI + d0);
    float4 ha = *(const float4*)(Sp + (size_t)t*64 + d0);
    float4 hb = *(const float4*)(Sp + (size_t)t*64 + d0 + 4);
    *(short8*)&h0l[swoff] = cvt8(ha, hb);
    short8 xv = *(const short8*)(xc + (size_t)(c0+t)*CD + h*HD + d0);
    int tc = t >> 3, ti = t & 7;
    #pragma unroll
    for (int e = 0; e < 8; ++e) {
      int p = d0 + e;
      xT[p*64 + ((tc ^ (p & 7))*8 + ti)] = (unsigned short)xv[e];
    }
  }
  __syncthreads();
  if (tid == 0) {
    float run = 0.f;
    for (int t = 0; t < 64; ++t) { run += lg[t]; pl[t] = run; }
  }
  __syncthreads();
  if (tid < 64) pe[tid] = expf(pl[tid]);
  __syncthreads();
  int t16 = lane & 15, q4 = lane >> 4;
  int t0 = 16*w;
  f32x4 zero = {0.f,0.f,0.f,0.f};
  f32x4 accG[4], accY[4];
  #pragma unroll
  for (int j = 0; j < 4; ++j) { accG[j] = zero; accY[j] = zero; }
  #pragma unroll
  for (int ks = 0; ks < 2; ++ks) {
    int rowA = t0 + t16;
    short8 a = *(const short8*)&Cl[rowA*64 + (((ks*4 + q4) ^ (rowA & 7))*8)];
    #pragma unroll
    for (int j = 0; j < 4; ++j) {
      int rowB = 16*j + t16;
      int off = rowB*64 + (((ks*4 + q4) ^ (rowB & 7))*8);
      accG[j] = __builtin_amdgcn_mfma_f32_16x16x32_bf16(a, *(const short8*)&Bl[off], accG[j], 0, 0, 0);
      accY[j] = __builtin_amdgcn_mfma_f32_16x16x32_bf16(a, *(const short8*)&h0l[off], accY[j], 0, 0, 0);
    }
  }
  // decay -> Gl (wave-private rows t0..t0+15), D on diagonal; scale accY by pe[t]
  #pragma unroll
  for (int j = 0; j < 4; ++j) {
    #pragma unroll
    for (int r = 0; r < 4; ++r) {
      int t = t0 + q4*4 + r;
      int s = 16*j + t16;
      float v = 0.f;
      if (s <= t) {
        v = accG[j][r] * dts[s] * expf(pl[t] - pl[s]);
        if (s == t) v += Dh;
      }
      Gl[t*64 + (((s >> 3) ^ (t & 7))*8 + (s & 7))] = f2bf(v);
    }
  }
  #pragma unroll
  for (int j = 0; j < 4; ++j)
    #pragma unroll
    for (int r = 0; r < 4; ++r)
      accY[j][r] *= pe[t0 + q4*4 + r];
  // Y += G . xT   (G rows are wave-private: no barrier, lgkm waits only)
  #pragma unroll
  for (int ks = 0; ks < 2; ++ks) {
    int rowA = t0 + t16;
    short8 a = *(const short8*)&Gl[rowA*64 + (((ks*4 + q4) ^ (rowA & 7))*8)];
    #pragma unroll
    for (int j = 0; j < 4; ++j) {
      int rowB = 16*j + t16;
      short8 b = *(const short8*)&xT[rowB*64 + (((ks*4 + q4) ^ (rowB & 7))*8)];
      accY[j] = __builtin_amdgcn_mfma_f32_16x16x32_bf16(a, b, accY[j], 0, 0, 0);
    }
  }
  #pragma unroll
  for (int j = 0; j < 4; ++j)
    #pragma unroll
    for (int r = 0; r < 4; ++r) {
      int t = t0 + q4*4 + r;
      int p = 16*j + t16;
      y[(size_t)(c0+t)*DI + h*HD + p] = accY[j][r];
    }
}

__global__ void fill_debug(float* out, float v) {
  int i = blockIdx.x*256 + threadIdx.x;
  if (i < L_TOK*DM) out[i] = v;
}

// ---------------- host ----------------

extern "C" void kernel_launch(void* const* d_in, const int* in_sizes, int n_in,
                              void* d_out, int out_size, void* d_ws, size_t ws_size,
                              hipStream_t stream) {
  const float* query = (const float*)d_in[0];
  const float* qpos  = (const float*)d_in[1];
  const float* pre_w = (const float*)d_in[2];
  const float* pre_b = (const float*)d_in[3];
  const float* fin_w = (const float*)d_in[4];
  const float* fin_b = (const float*)d_in[5];
  float* out = (float*)d_out;

  char* ws = (char*)d_ws;
  size_t off = 0;
  auto alloc = [&](size_t bytes) -> void* {
    void* p = ws + off;
    off += (bytes + 255) & ~(size_t)255;
    return p;
  };
  unsigned long long* keys = (unsigned long long*)alloc((size_t)2*L_TOK*8);
  unsigned int* ord = (unsigned int*)alloc((size_t)2*L_TOK*4);
  unsigned int* rpart = (unsigned int*)alloc((size_t)4*2*L_TOK*4);
  float* pmm  = (float*)alloc(256);
  float* qn   = (float*)alloc((size_t)L_TOK*DM*4);
  unsigned short* qnbf = (unsigned short*)alloc((size_t)L_TOK*DM*2);
  float* gate = (float*)alloc((size_t)L_TOK*DI*4);
  float* xbc  = (float*)alloc((size_t)L_TOK*CD*4);   // gemm_in out; reused as y (fp32) after conv
  unsigned short* convo = (unsigned short*)alloc((size_t)L_TOK*CD*2);
  float* dtb  = (float*)alloc((size_t)L_TOK*NH*4);
  float* Sbuf = (float*)alloc((size_t)NH*NC*4096*4);
  float* Pbuf = (float*)alloc((size_t)NH*NC*4);
  unsigned short* ybf = (unsigned short*)alloc((size_t)L_TOK*DI*2);
  unsigned short* WtA = (unsigned short*)alloc((size_t)1152*DM*2);
  unsigned short* WtO = (unsigned short*)alloc((size_t)DM*DI*2);
  if (off > ws_size) {
    fill_debug<<<(L_TOK*DM + 255)/256, 256, 0, stream>>>(out, (float)(ws_size >> 20));
    return;
  }

  minmax_kernel<<<1, 256, 0, stream>>>(qpos, pmm);
  hilbert_kernel<<<L_TOK/256, 256, 0, stream>>>(qpos, pmm, keys);
  rank_partial<<<dim3(L_TOK/256, 2, 4), 256, 0, stream>>>(keys, rpart);
  rank_scatter<<<(2*L_TOK)/256, 256, 0, stream>>>(keys, rpart, ord);
  hipMemcpyAsync(out, query, (size_t)L_TOK*DM*4, hipMemcpyDeviceToDevice, stream);

  for (int l = 0; l < 2; ++l) {
    int base = 6 + 8*l;
    const float* in_proj  = (const float*)d_in[base+0];
    const float* conv_w   = (const float*)d_in[base+1];
    const float* conv_b   = (const float*)d_in[base+2];
    const float* dt_bias  = (const float*)d_in[base+3];
    const float* A_log    = (const float*)d_in[base+4];
    const float* Dp       = (const float*)d_in[base+5];
    const float* norm_w   = (const float*)d_in[base+6];
    const float* out_proj = (const float*)d_in[base+7];

    ln_kernel<<<L_TOK/4, 256, 0, stream>>>(out, qn, qnbf, pre_w, pre_b);
    tcvt_in<<<(1152*DM)/256, 256, 0, stream>>>(in_proj, WtA);
    tcvt_out<<<(DM*DI)/256, 256, 0, stream>>>(out_proj, WtO);
    for (int dir = 0; dir < 2; ++dir) {
      const unsigned int* o = ord + (size_t)dir*L_TOK;
      gemm_in_mfma<<<dim3(9, L_TOK/128), 256, 0, stream>>>(qnbf, WtA, o, gate, xbc);
      dt_gemv<<<L_TOK/4, 256, 0, stream>>>(qn, in_proj, o, dt_bias, dtb);
      conv_kernel<<<(L_TOK*CD)/256, 256, 0, stream>>>(xbc, conv_w, conv_b, convo);
      phaseA_mfma<<<dim3(NC, NH), 256, 0, stream>>>(convo, dtb, A_log, Sbuf, Pbuf);
      phaseB_kernel<<<128, 256, 0, stream>>>(Sbuf, Pbuf);
      phaseC_mfma<<<dim3(NC, NH), 256, 0, stream>>>(convo, dtb, A_log, Dp, Sbuf, xbc);
      gating_kernel<<<L_TOK/4, 256, 0, stream>>>(xbc, gate, norm_w, ybf);
      gemm_out_mfma<<<dim3(2, L_TOK/128), 256, 0, stream>>>(ybf, WtO, o, out);
    }
    ln_kernel<<<L_TOK/4, 256, 0, stream>>>(out, out, (unsigned short*)nullptr, fin_w, fin_b);
  }
}

// Round 5
// 885.837 us; speedup vs baseline: 2.9016x; 1.1139x over previous
//
#include <hip/hip_runtime.h>
#include <stdint.h>

#define L_TOK 16384
#define DM 256
#define DI 512
#define DS 64
#define NH 8
#define HD 64
#define CD 640
#define DP 1160
#define CHUNK 64
#define NC 256
#define EPSF 1e-5f

typedef __attribute__((ext_vector_type(8))) short short8;
typedef __attribute__((ext_vector_type(4))) float f32x4;

#define GLL16(gp, lp) __builtin_amdgcn_global_load_lds((const __attribute__((address_space(1))) void*)(gp), (__attribute__((address_space(3))) void*)(lp), 16, 0, 0)

__device__ __forceinline__ float warp_sum(float v) {
  v += __shfl_xor(v, 1, 64);
  v += __shfl_xor(v, 2, 64);
  v += __shfl_xor(v, 4, 64);
  v += __shfl_xor(v, 8, 64);
  v += __shfl_xor(v, 16, 64);
  v += __shfl_xor(v, 32, 64);
  return v;
}

__device__ __forceinline__ float siluf(float x) { return x / (1.0f + expf(-x)); }

__device__ __forceinline__ unsigned short f2bf(float f) {
  unsigned int u = __float_as_uint(f);
  unsigned int r = (u + 0x7FFFu + ((u >> 16) & 1u)) >> 16;
  return (unsigned short)r;
}
__device__ __forceinline__ float bf2f(unsigned short u) {
  return __uint_as_float(((unsigned int)u) << 16);
}

// ---------------- serialization ----------------

__global__ __launch_bounds__(256) void minmax_kernel(const float* __restrict__ pos, float* __restrict__ pmm) {
  __shared__ float sm[6][256];
  int tid = threadIdx.x;
  float mn0=1e30f, mn1=1e30f, mn2=1e30f, mx0=-1e30f, mx1=-1e30f, mx2=-1e30f;
  for (int t = tid; t < L_TOK; t += 256) {
    float a = pos[t*3+0], b = pos[t*3+1], c = pos[t*3+2];
    mn0=fminf(mn0,a); mx0=fmaxf(mx0,a);
    mn1=fminf(mn1,b); mx1=fmaxf(mx1,b);
    mn2=fminf(mn2,c); mx2=fmaxf(mx2,c);
  }
  sm[0][tid]=mn0; sm[1][tid]=mn1; sm[2][tid]=mn2;
  sm[3][tid]=mx0; sm[4][tid]=mx1; sm[5][tid]=mx2;
  __syncthreads();
  for (int s = 128; s > 0; s >>= 1) {
    if (tid < s) {
      #pragma unroll
      for (int d = 0; d < 3; ++d) {
        sm[d][tid]   = fminf(sm[d][tid],   sm[d][tid+s]);
        sm[3+d][tid] = fmaxf(sm[3+d][tid], sm[3+d][tid+s]);
      }
    }
    __syncthreads();
  }
  if (tid < 6) pmm[tid] = sm[tid][0];
}

__device__ unsigned int hilbert3(unsigned int a, unsigned int b, unsigned int c) {
  unsigned int x0 = a, x1 = b, x2 = c;
  for (unsigned int Q = 512u; Q > 1u; Q >>= 1) {
    unsigned int P = Q - 1u;
    { if (x0 & Q) x0 ^= P; }
    {
      unsigned int t = (x0 ^ x1) & P;
      if (x1 & Q) { x0 ^= P; }
      else { x0 ^= t; x1 ^= t; }
    }
    {
      unsigned int t = (x0 ^ x2) & P;
      if (x2 & Q) { x0 ^= P; }
      else { x0 ^= t; x2 ^= t; }
    }
  }
  x1 ^= x0; x2 ^= x1;
  unsigned int tt = 0;
  for (unsigned int Q = 512u; Q > 1u; Q >>= 1)
    if (x2 & Q) tt ^= (Q - 1u);
  x0 ^= tt; x1 ^= tt; x2 ^= tt;
  unsigned int code = 0;
  #pragma unroll
  for (int bb = 9; bb >= 0; --bb) {
    code = (code << 1) | ((x0 >> bb) & 1u);
    code = (code << 1) | ((x1 >> bb) & 1u);
    code = (code << 1) | ((x2 >> bb) & 1u);
  }
  return code;
}

__global__ __launch_bounds__(256) void hilbert_kernel(const float* __restrict__ pos, const float* __restrict__ pmm,
                                                      unsigned long long* __restrict__ keys) {
  int t = blockIdx.x*256 + threadIdx.x;
  if (t >= L_TOK) return;
  unsigned int g[3];
  #pragma unroll
  for (int d = 0; d < 3; ++d) {
    float v = (pos[t*3+d] - pmm[d]) / (pmm[3+d] - pmm[d] + 1e-6f) * 1023.0f;
    v = fminf(fmaxf(v, 0.0f), 1023.0f);
    g[d] = (unsigned int)(int)v;
  }
  unsigned int ca = hilbert3(g[0], g[1], g[2]);
  unsigned int cb = hilbert3(g[1], g[0], g[2]);
  keys[t]         = ((unsigned long long)ca << 14) | (unsigned long long)t;
  keys[L_TOK + t] = ((unsigned long long)cb << 14) | (unsigned long long)t;
}

// all-pairs rank with 8-query register blocking; tile=1024 keys, 16 splits.
__global__ __launch_bounds__(256) void rank_partial(const unsigned long long* __restrict__ keys,
                                                    unsigned int* __restrict__ partial) {
  __shared__ unsigned long long tile[1024];
  int arr = blockIdx.y, ks = blockIdx.z;
  const unsigned long long* k = keys + (size_t)arr * L_TOK;
  int qbase = blockIdx.x*2048 + threadIdx.x;
  unsigned long long q[8];
  #pragma unroll
  for (int i = 0; i < 8; ++i) q[i] = k[qbase + 256*i];
  const unsigned long long* src = k + ks*1024;
  #pragma unroll
  for (int t = 0; t < 4; ++t) tile[threadIdx.x + 256*t] = src[threadIdx.x + 256*t];
  __syncthreads();
  unsigned int r[8] = {};
  const ulonglong2* t2 = (const ulonglong2*)tile;
  #pragma unroll 4
  for (int j = 0; j < 512; ++j) {
    ulonglong2 v = t2[j];
    #pragma unroll
    for (int i = 0; i < 8; ++i) {
      r[i] += (v.x < q[i]) ? 1u : 0u;
      r[i] += (v.y < q[i]) ? 1u : 0u;
    }
  }
  #pragma unroll
  for (int i = 0; i < 8; ++i)
    partial[(size_t)(ks*2 + arr)*L_TOK + qbase + 256*i] = r[i];
}

__global__ __launch_bounds__(256) void rank_scatter(const unsigned long long* __restrict__ keys,
                                                    const unsigned int* __restrict__ partial,
                                                    unsigned int* __restrict__ ord) {
  int i = blockIdx.x*256 + threadIdx.x;
  int arr = i >> 14;
  int qi = i & (L_TOK - 1);
  unsigned int r = 0;
  #pragma unroll
  for (int ks = 0; ks < 16; ++ks) r += partial[(size_t)(ks*2 + arr)*L_TOK + qi];
  ord[(size_t)arr*L_TOK + r] = (unsigned int)(keys[i] & 0x3FFFu);
}

// ---------------- layernorm / gating ----------------

__global__ __launch_bounds__(256) void ln_kernel(const float* __restrict__ in, float* __restrict__ out,
                                                 unsigned short* __restrict__ outbf,
                                                 const float* __restrict__ w, const float* __restrict__ b) {
  int row = blockIdx.x*4 + (threadIdx.x >> 6);
  int lane = threadIdx.x & 63;
  const float4 v = *(const float4*)(in + (size_t)row*DM + lane*4);
  float s = v.x + v.y + v.z + v.w;
  float mean = warp_sum(s) * (1.0f/DM);
  float4 xc = make_float4(v.x-mean, v.y-mean, v.z-mean, v.w-mean);
  float ss = xc.x*xc.x + xc.y*xc.y + xc.z*xc.z + xc.w*xc.w;
  ss = warp_sum(ss) * (1.0f/DM);
  float inv = rsqrtf(ss + EPSF);
  const float4 w4 = *(const float4*)(w + lane*4);
  const float4 b4 = *(const float4*)(b + lane*4);
  float4 o;
  o.x = xc.x*inv*w4.x + b4.x;
  o.y = xc.y*inv*w4.y + b4.y;
  o.z = xc.z*inv*w4.z + b4.z;
  o.w = xc.w*inv*w4.w + b4.w;
  *(float4*)(out + (size_t)row*DM + lane*4) = o;
  if (outbf) {
    ushort4 ob = make_ushort4(f2bf(o.x), f2bf(o.y), f2bf(o.z), f2bf(o.w));
    *(ushort4*)(outbf + (size_t)row*DM + lane*4) = ob;
  }
}

// in-place: ybf = bf16( rmsnorm( ybf * silu(gatebf) ) * nw )
__global__ __launch_bounds__(256) void gating_kernel(unsigned short* __restrict__ ybf,
                                                     const unsigned short* __restrict__ gatebf,
                                                     const float* __restrict__ nw) {
  int row = blockIdx.x*4 + (threadIdx.x >> 6);
  int lane = threadIdx.x & 63;
  unsigned short* yr = ybf + (size_t)row*DI;
  const unsigned short* gr = gatebf + (size_t)row*DI;
  ushort4 yu0 = *(const ushort4*)(yr + lane*4);
  ushort4 yu1 = *(const ushort4*)(yr + 256 + lane*4);
  ushort4 gu0 = *(const ushort4*)(gr + lane*4);
  ushort4 gu1 = *(const ushort4*)(gr + 256 + lane*4);
  float4 y0 = make_float4(bf2f(yu0.x), bf2f(yu0.y), bf2f(yu0.z), bf2f(yu0.w));
  float4 y1 = make_float4(bf2f(yu1.x), bf2f(yu1.y), bf2f(yu1.z), bf2f(yu1.w));
  y0.x *= siluf(bf2f(gu0.x)); y0.y *= siluf(bf2f(gu0.y)); y0.z *= siluf(bf2f(gu0.z)); y0.w *= siluf(bf2f(gu0.w));
  y1.x *= siluf(bf2f(gu1.x)); y1.y *= siluf(bf2f(gu1.y)); y1.z *= siluf(bf2f(gu1.z)); y1.w *= siluf(bf2f(gu1.w));
  float ss = y0.x*y0.x + y0.y*y0.y + y0.z*y0.z + y0.w*y0.w
           + y1.x*y1.x + y1.y*y1.y + y1.z*y1.z + y1.w*y1.w;
  ss = warp_sum(ss) * (1.0f/DI);
  float inv = rsqrtf(ss + EPSF);
  const float4 w0 = *(const float4*)(nw + lane*4);
  const float4 w1 = *(const float4*)(nw + 256 + lane*4);
  y0.x *= inv*w0.x; y0.y *= inv*w0.y; y0.z *= inv*w0.z; y0.w *= inv*w0.w;
  y1.x *= inv*w1.x; y1.y *= inv*w1.y; y1.z *= inv*w1.z; y1.w *= inv*w1.w;
  *(ushort4*)(yr + lane*4)       = make_ushort4(f2bf(y0.x), f2bf(y0.y), f2bf(y0.z), f2bf(y0.w));
  *(ushort4*)(yr + 256 + lane*4) = make_ushort4(f2bf(y1.x), f2bf(y1.y), f2bf(y1.z), f2bf(y1.w));
}

// ---------------- weight transpose+convert (both in one) ----------------

__global__ __launch_bounds__(256) void tcvt_both(const float* __restrict__ Wi, const float* __restrict__ Wo,
                                                 unsigned short* __restrict__ WtA, unsigned short* __restrict__ WtO) {
  int idx = blockIdx.x*256 + threadIdx.x;
  if (idx < 1152*DM) {
    int n = idx >> 8, k = idx & 255;
    WtA[idx] = f2bf(Wi[(size_t)k*DP + n]);
  } else {
    int j = idx - 1152*DM;
    int n = j >> 9, k = j & 511;
    WtO[j] = f2bf(Wo[(size_t)k*DM + n]);
  }
}

// ---------------- MFMA GEMMs ----------------

__global__ __launch_bounds__(256) void gemm_in_mfma(const unsigned short* __restrict__ Abf,
                                                    const unsigned short* __restrict__ Wt,
                                                    const unsigned int* __restrict__ ordp,
                                                    unsigned short* __restrict__ gatebf,
                                                    unsigned short* __restrict__ xbcbf) {
  __shared__ unsigned short Alds[128*64];
  __shared__ unsigned short Blds[128*64];
  int tid = threadIdx.x, lane = tid & 63, w = tid >> 6;
  int rb = blockIdx.y*128, cb = blockIdx.x*128;
  int wm = (w & 1)*64, wn = (w >> 1)*64;
  const unsigned short* pA[4]; const unsigned short* pB[4];
  unsigned short* dA[4]; unsigned short* dB[4];
  #pragma unroll
  for (int s = 0; s < 4; ++s) {
    int inst = w*4 + s;
    int r = inst*8 + (lane >> 3);
    int cA = (lane & 7) ^ (r & 7);
    pA[s] = Abf + (size_t)ordp[rb + r]*DM + cA*8;
    pB[s] = Wt + (size_t)(cb + r)*DM + cA*8;
    dA[s] = &Alds[inst*512];
    dB[s] = &Blds[inst*512];
  }
  f32x4 zero = {0.f, 0.f, 0.f, 0.f};
  f32x4 acc[4][4];
  #pragma unroll
  for (int i = 0; i < 4; ++i)
    #pragma unroll
    for (int j = 0; j < 4; ++j) acc[i][j] = zero;
  int t = lane & 15, q = lane >> 4;
  for (int k0 = 0; k0 < DM; k0 += 64) {
    #pragma unroll
    for (int s = 0; s < 4; ++s) GLL16(pA[s] + k0, dA[s]);
    #pragma unroll
    for (int s = 0; s < 4; ++s) GLL16(pB[s] + k0, dB[s]);
    __syncthreads();
    #pragma unroll
    for (int ks = 0; ks < 2; ++ks) {
      short8 af[4], bfr[4];
      int cc = ks*4 + q;
      #pragma unroll
      for (int i = 0; i < 4; ++i) {
        int rr = wm + 16*i + t;
        af[i] = *(const short8*)&Alds[rr*64 + ((cc ^ (rr & 7))*8)];
      }
      #pragma unroll
      for (int j = 0; j < 4; ++j) {
        int rr = wn + 16*j + t;
        bfr[j] = *(const short8*)&Blds[rr*64 + ((cc ^ (rr & 7))*8)];
      }
      #pragma unroll
      for (int i = 0; i < 4; ++i)
        #pragma unroll
        for (int j = 0; j < 4; ++j)
          acc[i][j] = __builtin_amdgcn_mfma_f32_16x16x32_bf16(af[i], bfr[j], acc[i][j], 0, 0, 0);
    }
    __syncthreads();
  }
  unsigned short* dst; int ld;
  if (cb < DI) { dst = gatebf + cb; ld = DI; }
  else         { dst = xbcbf + (cb - DI); ld = CD; }
  #pragma unroll
  for (int i = 0; i < 4; ++i) {
    int rowb = rb + wm + 16*i + q*4;
    #pragma unroll
    for (int j = 0; j < 4; ++j) {
      int col = wn + 16*j + t;
      #pragma unroll
      for (int r = 0; r < 4; ++r)
        dst[(size_t)(rowb + r)*ld + col] = f2bf(acc[i][j][r]);
    }
  }
}

__global__ __launch_bounds__(256) void gemm_out_mfma(const unsigned short* __restrict__ Abf,
                                                     const unsigned short* __restrict__ Wt,
                                                     const unsigned int* __restrict__ ordp,
                                                     float* __restrict__ out) {
  __shared__ unsigned short Alds[128*64];
  __shared__ unsigned short Blds[128*64];
  __shared__ unsigned int ordl[128];
  int tid = threadIdx.x, lane = tid & 63, w = tid >> 6;
  int rb = blockIdx.y*128, cb = blockIdx.x*128;
  int wm = (w & 1)*64, wn = (w >> 1)*64;
  if (tid < 128) ordl[tid] = ordp[rb + tid];
  const unsigned short* pA[4]; const unsigned short* pB[4];
  unsigned short* dA[4]; unsigned short* dB[4];
  #pragma unroll
  for (int s = 0; s < 4; ++s) {
    int inst = w*4 + s;
    int r = inst*8 + (lane >> 3);
    int cA = (lane & 7) ^ (r & 7);
    pA[s] = Abf + (size_t)(rb + r)*DI + cA*8;
    pB[s] = Wt + (size_t)(cb + r)*DI + cA*8;
    dA[s] = &Alds[inst*512];
    dB[s] = &Blds[inst*512];
  }
  f32x4 zero = {0.f, 0.f, 0.f, 0.f};
  f32x4 acc[4][4];
  #pragma unroll
  for (int i = 0; i < 4; ++i)
    #pragma unroll
    for (int j = 0; j < 4; ++j) acc[i][j] = zero;
  int t = lane & 15, q = lane >> 4;
  for (int k0 = 0; k0 < DI; k0 += 64) {
    #pragma unroll
    for (int s = 0; s < 4; ++s) GLL16(pA[s] + k0, dA[s]);
    #pragma unroll
    for (int s = 0; s < 4; ++s) GLL16(pB[s] + k0, dB[s]);
    __syncthreads();
    #pragma unroll
    for (int ks = 0; ks < 2; ++ks) {
      short8 af[4], bfr[4];
      int cc = ks*4 + q;
      #pragma unroll
      for (int i = 0; i < 4; ++i) {
        int rr = wm + 16*i + t;
        af[i] = *(const short8*)&Alds[rr*64 + ((cc ^ (rr & 7))*8)];
      }
      #pragma unroll
      for (int j = 0; j < 4; ++j) {
        int rr = wn + 16*j + t;
        bfr[j] = *(const short8*)&Blds[rr*64 + ((cc ^ (rr & 7))*8)];
      }
      #pragma unroll
      for (int i = 0; i < 4; ++i)
        #pragma unroll
        for (int j = 0; j < 4; ++j)
          acc[i][j] = __builtin_amdgcn_mfma_f32_16x16x32_bf16(af[i], bfr[j], acc[i][j], 0, 0, 0);
    }
    __syncthreads();
  }
  #pragma unroll
  for (int i = 0; i < 4; ++i) {
    #pragma unroll
    for (int r = 0; r < 4; ++r) {
      unsigned int tok = ordl[wm + 16*i + q*4 + r];
      float* op = out + (size_t)tok*DM + cb;
      #pragma unroll
      for (int j = 0; j < 4; ++j) {
        int col = wn + 16*j + t;
        op[col] += 0.5f*acc[i][j][r];
      }
    }
  }
}

// ---------------- dt path (fp32, fused softplus) ----------------
__global__ __launch_bounds__(256) void dt_gemv(const float* __restrict__ qn, const float* __restrict__ W,
                                               const unsigned int* __restrict__ ordp,
                                               const float* __restrict__ dt_bias, float* __restrict__ dtb) {
  int row = blockIdx.x*4 + (threadIdx.x >> 6);
  int lane = threadIdx.x & 63;
  unsigned int src = ordp[row];
  const float4 q4 = *(const float4*)(qn + (size_t)src*DM + lane*4);
  float a[8] = {0,0,0,0,0,0,0,0};
  const float* wp = W + (size_t)(lane*4)*DP + (DI + CD);
  float qe[4] = {q4.x, q4.y, q4.z, q4.w};
  #pragma unroll
  for (int e = 0; e < 4; ++e) {
    float4 wa = *(const float4*)(wp + (size_t)e*DP);
    float4 wb = *(const float4*)(wp + (size_t)e*DP + 4);
    a[0] += qe[e]*wa.x; a[1] += qe[e]*wa.y; a[2] += qe[e]*wa.z; a[3] += qe[e]*wa.w;
    a[4] += qe[e]*wb.x; a[5] += qe[e]*wb.y; a[6] += qe[e]*wb.z; a[7] += qe[e]*wb.w;
  }
  #pragma unroll
  for (int h = 0; h < 8; ++h) a[h] = warp_sum(a[h]);
  float v = 0.0f;
  #pragma unroll
  for (int h = 0; h < 8; ++h) if (lane == h) v = a[h];
  if (lane < 8) {
    v += dt_bias[lane];
    float sp = (v > 0.0f) ? (v + log1pf(expf(-v))) : log1pf(expf(v));
    dtb[(size_t)row*NH + lane] = sp;
  }
}

// ---------------- conv (bf16 in, bf16 out) ----------------

__global__ __launch_bounds__(256) void conv_kernel(const unsigned short* __restrict__ xbc, const float* __restrict__ cw,
                                                   const float* __restrict__ cbias, unsigned short* __restrict__ outc) {
  int idx = blockIdx.x*256 + threadIdx.x;
  if (idx >= L_TOK*CD) return;
  int c = idx % CD;
  int t = idx / CD;
  float s = cbias[c];
  #pragma unroll
  for (int kk = 0; kk < 4; ++kk) {
    int tt = t - 3 + kk;
    if (tt >= 0) s += cw[c*4+kk] * bf2f(xbc[(size_t)tt*CD + c]);
  }
  outc[idx] = f2bf(siluf(s));
}

// ---------------- chunked scan (MFMA, bf16 S) ----------------

__global__ __launch_bounds__(256) void phaseA_mfma(const unsigned short* __restrict__ xc,
                                                   const float* __restrict__ dtb, const float* __restrict__ A_log,
                                                   unsigned short* __restrict__ S, float* __restrict__ P) {
  int c = blockIdx.x, h = blockIdx.y, tid = threadIdx.x;
  int lane = tid & 63, w = tid >> 6;
  __shared__ unsigned short xT[64*64];
  __shared__ unsigned short Bt[64*64];
  __shared__ float dts[64], lg[64], sfx[64], wgt[64];
  __shared__ float totals;
  int c0 = c*CHUNK;
  float Ah = -expf(A_log[h]);
  if (tid < 64) {
    float dtv = dtb[(size_t)(c0+tid)*NH + h];
    dts[tid] = dtv; lg[tid] = dtv*Ah;
  }
  #pragma unroll
  for (int i = 0; i < 2; ++i) {
    int q = tid + 256*i;
    int t = q >> 3, s0 = (q & 7)*8;
    short8 v = *(const short8*)(xc + (size_t)(c0+t)*CD + DI + s0);
    int tc = t >> 3, ti = t & 7;
    #pragma unroll
    for (int e = 0; e < 8; ++e) {
      int s = s0 + e;
      Bt[s*64 + ((tc ^ (s & 7))*8 + ti)] = (unsigned short)v[e];
    }
  }
  __syncthreads();
  if (tid == 0) {
    float run = 0.f;
    for (int t = 63; t >= 0; --t) { sfx[t] = run; run += lg[t]; }
    totals = run;
  }
  __syncthreads();
  if (tid < 64) wgt[tid] = dts[tid]*expf(sfx[tid]);
  if (tid == 0) P[h*NC + c] = expf(totals);
  __syncthreads();
  #pragma unroll
  for (int i = 0; i < 2; ++i) {
    int q = tid + 256*i;
    int t = q >> 3, p0 = (q & 7)*8;
    short8 v = *(const short8*)(xc + (size_t)(c0+t)*CD + h*HD + p0);
    float wv = wgt[t];
    int tc = t >> 3, ti = t & 7;
    #pragma unroll
    for (int e = 0; e < 8; ++e) {
      int p = p0 + e;
      xT[p*64 + ((tc ^ (p & 7))*8 + ti)] = f2bf(bf2f((unsigned short)v[e]) * wv);
    }
  }
  __syncthreads();
  int t16 = lane & 15, q4 = lane >> 4;
  f32x4 zero = {0.f,0.f,0.f,0.f};
  f32x4 acc[4];
  #pragma unroll
  for (int j = 0; j < 4; ++j) acc[j] = zero;
  #pragma unroll
  for (int ks = 0; ks < 2; ++ks) {
    int rowA = 16*w + t16;
    short8 a = *(const short8*)&xT[rowA*64 + (((ks*4 + q4) ^ (rowA & 7))*8)];
    #pragma unroll
    for (int j = 0; j < 4; ++j) {
      int rowB = 16*j + t16;
      short8 b = *(const short8*)&Bt[rowB*64 + (((ks*4 + q4) ^ (rowB & 7))*8)];
      acc[j] = __builtin_amdgcn_mfma_f32_16x16x32_bf16(a, b, acc[j], 0, 0, 0);
    }
  }
  unsigned short* Sp = S + ((size_t)(h*NC + c))*4096;
  #pragma unroll
  for (int j = 0; j < 4; ++j)
    #pragma unroll
    for (int r = 0; r < 4; ++r)
      Sp[(size_t)(16*w + q4*4 + r)*64 + 16*j + t16] = f2bf(acc[j][r]);
}

// ---- phaseB split: 16 superchunks x 16 chunks, fp32 carry, bf16 storage ----
// gid -> h = gid>>15, sc = (gid>>11)&15, e2 = gid&2047 (elem pair)

__global__ __launch_bounds__(256) void phaseB1(const unsigned short* __restrict__ S, const float* __restrict__ P,
                                               float* __restrict__ Ssum, float* __restrict__ Psum) {
  int gid = blockIdx.x*256 + threadIdx.x;
  int e2 = gid & 2047;
  int sc = (gid >> 11) & 15;
  int h  = gid >> 15;
  const unsigned short* base = S + ((size_t)(h*NC + sc*16))*4096 + e2*2;
  const float* Ph = P + h*NC + sc*16;
  float hx = 0.f, hy = 0.f, pprod = 1.f;
  #pragma unroll
  for (int k = 0; k < 16; ++k) {
    unsigned int v = *(const unsigned int*)(base + (size_t)k*4096);
    float p = Ph[k];
    hx = p*hx + bf2f((unsigned short)(v & 0xffffu));
    hy = p*hy + bf2f((unsigned short)(v >> 16));
    pprod *= p;
  }
  float* sp = Ssum + ((size_t)(h*16 + sc))*4096 + e2*2;
  sp[0] = hx; sp[1] = hy;
  if (e2 == 0) Psum[h*16 + sc] = pprod;
}

__global__ __launch_bounds__(256) void phaseB3(unsigned short* __restrict__ S, const float* __restrict__ P,
                                               const float* __restrict__ Ssum, const float* __restrict__ Psum) {
  int gid = blockIdx.x*256 + threadIdx.x;
  int e2 = gid & 2047;
  int sc = (gid >> 11) & 15;
  int h  = gid >> 15;
  float hx = 0.f, hy = 0.f;
  for (int s2 = 0; s2 < sc; ++s2) {
    float pp = Psum[h*16 + s2];
    const float* sp = Ssum + ((size_t)(h*16 + s2))*4096 + e2*2;
    hx = pp*hx + sp[0];
    hy = pp*hy + sp[1];
  }
  unsigned short* base = S + ((size_t)(h*NC + sc*16))*4096 + e2*2;
  const float* Ph = P + h*NC + sc*16;
  #pragma unroll
  for (int k = 0; k < 16; ++k) {
    unsigned int* ptr = (unsigned int*)(base + (size_t)k*4096);
    unsigned int v = *ptr;
    float p = Ph[k];
    *ptr = (unsigned int)f2bf(hx) | ((unsigned int)f2bf(hy) << 16);
    hx = p*hx + bf2f((unsigned short)(v & 0xffffu));
    hy = p*hy + bf2f((unsigned short)(v >> 16));
  }
}

// phaseC: Y bf16 out
__global__ __launch_bounds__(256) void phaseC_mfma(const unsigned short* __restrict__ xc,
                                                   const float* __restrict__ dtb, const float* __restrict__ A_log,
                                                   const float* __restrict__ Dp,
                                                   const unsigned short* __restrict__ S,
                                                   unsigned short* __restrict__ y) {
  int c = blockIdx.x, h = blockIdx.y, tid = threadIdx.x;
  int lane = tid & 63, w = tid >> 6;
  __shared__ unsigned short Cl[64*64];
  __shared__ unsigned short Bl[64*64];
  __shared__ unsigned short h0l[64*64];
  __shared__ unsigned short xT[64*64];
  __shared__ unsigned short Gl[64*64];
  __shared__ float dts[64], lg[64], pl[64], pe[64];
  int c0 = c*CHUNK;
  float Ah = -expf(A_log[h]);
  float Dh = Dp[h];
  if (tid < 64) {
    float dtv = dtb[(size_t)(c0+tid)*NH + h];
    dts[tid] = dtv; lg[tid] = dtv*Ah;
  }
  const unsigned short* Sp = S + ((size_t)(h*NC + c))*4096;
  #pragma unroll
  for (int i = 0; i < 2; ++i) {
    int q = tid + 256*i;
    int t = q >> 3, d0 = (q & 7)*8;
    int swoff = t*64 + (((q & 7) ^ (t & 7))*8);
    *(short8*)&Cl[swoff] = *(const short8*)(xc + (size_t)(c0+t)*CD + DI + DS + d0);
    *(short8*)&Bl[swoff] = *(const short8*)(xc + (size_t)(c0+t)*CD + DI + d0);
    *(short8*)&h0l[swoff] = *(const short8*)(Sp + (size_t)t*64 + d0);
    short8 xv = *(const short8*)(xc + (size_t)(c0+t)*CD + h*HD + d0);
    int tc = t >> 3, ti = t & 7;
    #pragma unroll
    for (int e = 0; e < 8; ++e) {
      int p = d0 + e;
      xT[p*64 + ((tc ^ (p & 7))*8 + ti)] = (unsigned short)xv[e];
    }
  }
  __syncthreads();
  if (tid == 0) {
    float run = 0.f;
    for (int t = 0; t < 64; ++t) { run += lg[t]; pl[t] = run; }
  }
  __syncthreads();
  if (tid < 64) pe[tid] = expf(pl[tid]);
  __syncthreads();
  int t16 = lane & 15, q4 = lane >> 4;
  int t0 = 16*w;
  f32x4 zero = {0.f,0.f,0.f,0.f};
  f32x4 accG[4], accY[4];
  #pragma unroll
  for (int j = 0; j < 4; ++j) { accG[j] = zero; accY[j] = zero; }
  #pragma unroll
  for (int ks = 0; ks < 2; ++ks) {
    int rowA = t0 + t16;
    short8 a = *(const short8*)&Cl[rowA*64 + (((ks*4 + q4) ^ (rowA & 7))*8)];
    #pragma unroll
    for (int j = 0; j < 4; ++j) {
      int rowB = 16*j + t16;
      int off = rowB*64 + (((ks*4 + q4) ^ (rowB & 7))*8);
      accG[j] = __builtin_amdgcn_mfma_f32_16x16x32_bf16(a, *(const short8*)&Bl[off], accG[j], 0, 0, 0);
      accY[j] = __builtin_amdgcn_mfma_f32_16x16x32_bf16(a, *(const short8*)&h0l[off], accY[j], 0, 0, 0);
    }
  }
  #pragma unroll
  for (int j = 0; j < 4; ++j) {
    #pragma unroll
    for (int r = 0; r < 4; ++r) {
      int t = t0 + q4*4 + r;
      int s = 16*j + t16;
      float v = 0.f;
      if (s <= t) {
        v = accG[j][r] * dts[s] * expf(pl[t] - pl[s]);
        if (s == t) v += Dh;
      }
      Gl[t*64 + (((s >> 3) ^ (t & 7))*8 + (s & 7))] = f2bf(v);
    }
  }
  #pragma unroll
  for (int j = 0; j < 4; ++j)
    #pragma unroll
    for (int r = 0; r < 4; ++r)
      accY[j][r] *= pe[t0 + q4*4 + r];
  #pragma unroll
  for (int ks = 0; ks < 2; ++ks) {
    int rowA = t0 + t16;
    short8 a = *(const short8*)&Gl[rowA*64 + (((ks*4 + q4) ^ (rowA & 7))*8)];
    #pragma unroll
    for (int j = 0; j < 4; ++j) {
      int rowB = 16*j + t16;
      short8 b = *(const short8*)&xT[rowB*64 + (((ks*4 + q4) ^ (rowB & 7))*8)];
      accY[j] = __builtin_amdgcn_mfma_f32_16x16x32_bf16(a, b, accY[j], 0, 0, 0);
    }
  }
  #pragma unroll
  for (int j = 0; j < 4; ++j)
    #pragma unroll
    for (int r = 0; r < 4; ++r) {
      int t = t0 + q4*4 + r;
      int p = 16*j + t16;
      y[(size_t)(c0+t)*DI + h*HD + p] = f2bf(accY[j][r]);
    }
}

__global__ void fill_debug(float* out, float v) {
  int i = blockIdx.x*256 + threadIdx.x;
  if (i < L_TOK*DM) out[i] = v;
}

// ---------------- host ----------------

extern "C" void kernel_launch(void* const* d_in, const int* in_sizes, int n_in,
                              void* d_out, int out_size, void* d_ws, size_t ws_size,
                              hipStream_t stream) {
  const float* query = (const float*)d_in[0];
  const float* qpos  = (const float*)d_in[1];
  const float* pre_w = (const float*)d_in[2];
  const float* pre_b = (const float*)d_in[3];
  const float* fin_w = (const float*)d_in[4];
  const float* fin_b = (const float*)d_in[5];
  float* out = (float*)d_out;

  char* ws = (char*)d_ws;
  size_t off = 0;
  auto alloc = [&](size_t bytes) -> void* {
    void* p = ws + off;
    off += (bytes + 255) & ~(size_t)255;
    return p;
  };
  unsigned long long* keys = (unsigned long long*)alloc((size_t)2*L_TOK*8);
  unsigned int* ord = (unsigned int*)alloc((size_t)2*L_TOK*4);
  unsigned int* rpart = (unsigned int*)alloc((size_t)16*2*L_TOK*4);
  float* pmm  = (float*)alloc(256);
  float* qn   = (float*)alloc((size_t)L_TOK*DM*4);
  unsigned short* qnbf = (unsigned short*)alloc((size_t)L_TOK*DM*2);
  unsigned short* gatebf = (unsigned short*)alloc((size_t)L_TOK*DI*2);
  unsigned short* xbcbf  = (unsigned short*)alloc((size_t)L_TOK*CD*2);
  unsigned short* convo = (unsigned short*)alloc((size_t)L_TOK*CD*2);
  float* dtb  = (float*)alloc((size_t)L_TOK*NH*4);
  unsigned short* Sbuf = (unsigned short*)alloc((size_t)NH*NC*4096*2);
  float* Pbuf = (float*)alloc((size_t)NH*NC*4);
  float* Ssum = (float*)alloc((size_t)NH*16*4096*4);
  float* Psum = (float*)alloc((size_t)NH*16*4);
  unsigned short* ybf = (unsigned short*)alloc((size_t)L_TOK*DI*2);
  unsigned short* WtA = (unsigned short*)alloc((size_t)1152*DM*2);
  unsigned short* WtO = (unsigned short*)alloc((size_t)DM*DI*2);
  if (off > ws_size) {
    fill_debug<<<(L_TOK*DM + 255)/256, 256, 0, stream>>>(out, (float)(ws_size >> 20));
    return;
  }

  minmax_kernel<<<1, 256, 0, stream>>>(qpos, pmm);
  hilbert_kernel<<<L_TOK/256, 256, 0, stream>>>(qpos, pmm, keys);
  rank_partial<<<dim3(8, 2, 16), 256, 0, stream>>>(keys, rpart);
  rank_scatter<<<(2*L_TOK)/256, 256, 0, stream>>>(keys, rpart, ord);
  hipMemcpyAsync(out, query, (size_t)L_TOK*DM*4, hipMemcpyDeviceToDevice, stream);

  for (int l = 0; l < 2; ++l) {
    int base = 6 + 8*l;
    const float* in_proj  = (const float*)d_in[base+0];
    const float* conv_w   = (const float*)d_in[base+1];
    const float* conv_b   = (const float*)d_in[base+2];
    const float* dt_bias  = (const float*)d_in[base+3];
    const float* A_log    = (const float*)d_in[base+4];
    const float* Dp       = (const float*)d_in[base+5];
    const float* norm_w   = (const float*)d_in[base+6];
    const float* out_proj = (const float*)d_in[base+7];

    ln_kernel<<<L_TOK/4, 256, 0, stream>>>(out, qn, qnbf, pre_w, pre_b);
    tcvt_both<<<(1152*DM + DM*DI)/256, 256, 0, stream>>>(in_proj, out_proj, WtA, WtO);
    for (int dir = 0; dir < 2; ++dir) {
      const unsigned int* o = ord + (size_t)dir*L_TOK;
      gemm_in_mfma<<<dim3(9, L_TOK/128), 256, 0, stream>>>(qnbf, WtA, o, gatebf, xbcbf);
      dt_gemv<<<L_TOK/4, 256, 0, stream>>>(qn, in_proj, o, dt_bias, dtb);
      conv_kernel<<<(L_TOK*CD)/256, 256, 0, stream>>>(xbcbf, conv_w, conv_b, convo);
      phaseA_mfma<<<dim3(NC, NH), 256, 0, stream>>>(convo, dtb, A_log, Sbuf, Pbuf);
      phaseB1<<<(NH*16*2048)/256, 256, 0, stream>>>(Sbuf, Pbuf, Ssum, Psum);
      phaseB3<<<(NH*16*2048)/256, 256, 0, stream>>>(Sbuf, Pbuf, Ssum, Psum);
      phaseC_mfma<<<dim3(NC, NH), 256, 0, stream>>>(convo, dtb, A_log, Dp, Sbuf, ybf);
      gating_kernel<<<L_TOK/4, 256, 0, stream>>>(ybf, gatebf, norm_w);
      gemm_out_mfma<<<dim3(2, L_TOK/128), 256, 0, stream>>>(ybf, WtO, o, out);
    }
    ln_kernel<<<L_TOK/4, 256, 0, stream>>>(out, out, (unsigned short*)nullptr, fin_w, fin_b);
  }
}